// Round 8
// baseline (215.364 us; speedup 1.0000x reference)
//
#include <hip/hip_runtime.h>

static constexpr int NN = 50000;    // nodes
static constexpr int NE = 1600000;  // edges
static constexpr int CH = 128;
static constexpr int NCLS = 40;
static constexpr size_t BF_BYTES = (size_t)NN * CH * 2;   // 12.8 MB bf16 matrix

static constexpr int NPB  = 64;                        // nodes per bucket
static constexpr int NBUK = (NN + NPB - 1) / NPB;      // 782
static constexpr int EPB  = 8192;                      // edges per hist block
static constexpr int NHB  = (NE + EPB - 1) / EPB;      // 196
static constexpr int NS   = NBUK * NHB;                // 153272 hist entries
static constexpr int SCAN_B = 256;
static constexpr int NSB  = (NS + SCAN_B - 1) / SCAN_B; // 599 (<=1024)

typedef __attribute__((ext_vector_type(8))) short bf16x8;
typedef __attribute__((ext_vector_type(4))) float f32x4;

// ---- bf16 helpers (bit-level, RNE) ----
__device__ __forceinline__ float bflo(unsigned v) {
    return __uint_as_float((v & 0xFFFFu) << 16);
}
__device__ __forceinline__ float bfhi(unsigned v) {
    return __uint_as_float(v & 0xFFFF0000u);
}
__device__ __forceinline__ unsigned short f2bf(float f) {
    unsigned u = __float_as_uint(f);
    u += 0x7FFFu + ((u >> 16) & 1u);   // round to nearest even
    return (unsigned short)(u >> 16);
}

// ---------------------------------------------------------------------------
// H1 = relu(F @ W1 + b1) via bf16 MFMA. Block: 256 thr (4 waves), 64 rows.
// ---------------------------------------------------------------------------
__global__ __launch_bounds__(256)
void gemm1_mfma(const float* __restrict__ X, const float* __restrict__ W,
                const float* __restrict__ b, unsigned short* __restrict__ Y)
{
    constexpr int PAD = 136;
    __shared__ unsigned short Wt[128 * PAD];       // W1^T bf16 [c][k]
    __shared__ unsigned short Fa[64 * PAD];        // F tile bf16 [r][k]
    __shared__ float bl[128];

    const int t = threadIdx.x;
    const int lane = t & 63;
    const int w = t >> 6;

    {
        const int k = t >> 1;
        const int c0 = (t & 1) * 64;
        #pragma unroll 4
        for (int j = 0; j < 64; j += 4) {
            const float4 v = *reinterpret_cast<const float4*>(&W[k * 128 + c0 + j]);
            Wt[(c0 + j + 0) * PAD + k] = f2bf(v.x);
            Wt[(c0 + j + 1) * PAD + k] = f2bf(v.y);
            Wt[(c0 + j + 2) * PAD + k] = f2bf(v.z);
            Wt[(c0 + j + 3) * PAD + k] = f2bf(v.w);
        }
    }
    if (t < 128) bl[t] = b[t];

    const int base = blockIdx.x * 64;
    const int nRows = min(64, NN - base);
    {
        const int r = t >> 2;
        const int c0 = (t & 3) * 32;
        if (r < nRows) {
            #pragma unroll
            for (int j = 0; j < 32; j += 4) {
                const float4 v = *reinterpret_cast<const float4*>(&X[(size_t)(base + r) * CH + c0 + j]);
                ushort4 o; o.x = f2bf(v.x); o.y = f2bf(v.y); o.z = f2bf(v.z); o.w = f2bf(v.w);
                *reinterpret_cast<ushort4*>(&Fa[r * PAD + c0 + j]) = o;
            }
        } else {
            #pragma unroll
            for (int j = 0; j < 32; j += 4) {
                ushort4 z; z.x = z.y = z.z = z.w = 0;
                *reinterpret_cast<ushort4*>(&Fa[r * PAD + c0 + j]) = z;
            }
        }
    }
    __syncthreads();

    f32x4 acc[8];
    #pragma unroll
    for (int i = 0; i < 8; ++i) acc[i] = (f32x4){0.f, 0.f, 0.f, 0.f};

    const int arow = w * 16 + (lane & 15);
    const int kgrp = (lane >> 4) * 4;

    #pragma unroll
    for (int ks = 0; ks < 4; ++ks) {
        const int k0 = ks * 32 + kgrp;
        bf16x8 af;
        {
            const short4 lo = *reinterpret_cast<const short4*>(&Fa[arow * PAD + k0]);
            const short4 hi = *reinterpret_cast<const short4*>(&Fa[arow * PAD + k0 + 16]);
            af[0] = lo.x; af[1] = lo.y; af[2] = lo.z; af[3] = lo.w;
            af[4] = hi.x; af[5] = hi.y; af[6] = hi.z; af[7] = hi.w;
        }
        #pragma unroll
        for (int ct = 0; ct < 8; ++ct) {
            const int c = ct * 16 + (lane & 15);
            bf16x8 bf;
            const short4 lo = *reinterpret_cast<const short4*>(&Wt[c * PAD + k0]);
            const short4 hi = *reinterpret_cast<const short4*>(&Wt[c * PAD + k0 + 16]);
            bf[0] = lo.x; bf[1] = lo.y; bf[2] = lo.z; bf[3] = lo.w;
            bf[4] = hi.x; bf[5] = hi.y; bf[6] = hi.z; bf[7] = hi.w;
            acc[ct] = __builtin_amdgcn_mfma_f32_16x16x32_bf16(af, bf, acc[ct], 0, 0, 0);
        }
    }
    __syncthreads();

    #pragma unroll
    for (int ct = 0; ct < 8; ++ct) {
        const int c = ct * 16 + (lane & 15);
        const float bias = bl[c];
        #pragma unroll
        for (int r = 0; r < 4; ++r) {
            const int row = w * 16 + (lane >> 4) * 4 + r;
            Fa[row * PAD + c] = f2bf(fmaxf(acc[ct][r] + bias, 0.f));
        }
    }
    __syncthreads();

    {
        const int r = t >> 2;
        const int c0 = (t & 3) * 32;
        if (r < nRows) {
            #pragma unroll
            for (int j = 0; j < 32; j += 8) {
                const ulong2 v = *reinterpret_cast<const ulong2*>(&Fa[r * PAD + c0 + j]);
                *reinterpret_cast<ulong2*>(&Y[(size_t)(base + r) * CH + c0 + j]) = v;
            }
        }
    }
}

// ---------------------------------------------------------------------------
// Bucketing: per-block LDS histogram over 782 coarse buckets (src>>6)
// ---------------------------------------------------------------------------
__global__ __launch_bounds__(256)
void bucket_hist(const int* __restrict__ src, int* __restrict__ H)
{
    __shared__ int h[NBUK];
    const int t = threadIdx.x;
    for (int i = t; i < NBUK; i += 256) h[i] = 0;
    __syncthreads();
    const int e0 = blockIdx.x * EPB;
    for (int i = t; i < EPB; i += 256) {
        const int e = e0 + i;
        if (e < NE) atomicAdd(&h[src[e] >> 6], 1);
    }
    __syncthreads();
    for (int i = t; i < NBUK; i += 256) H[i * NHB + blockIdx.x] = h[i];
}

__global__ __launch_bounds__(SCAN_B)
void scan_local(int* __restrict__ H, int* __restrict__ bsum)
{
    __shared__ int buf[SCAN_B];
    const int t = threadIdx.x;
    const int g = blockIdx.x * SCAN_B + t;
    const int v = (g < NS) ? H[g] : 0;
    buf[t] = v;
    __syncthreads();
    #pragma unroll
    for (int off = 1; off < SCAN_B; off <<= 1) {
        const int x = (t >= off) ? buf[t - off] : 0;
        __syncthreads();
        buf[t] += x;
        __syncthreads();
    }
    if (g < NS) H[g] = buf[t] - v;
    if (t == SCAN_B - 1) bsum[blockIdx.x] = buf[t];
}

__global__ __launch_bounds__(1024)
void scan_bsums(int* __restrict__ bsum)
{
    __shared__ int buf[1024];
    const int t = threadIdx.x;
    const int v = (t < NSB) ? bsum[t] : 0;
    buf[t] = v;
    __syncthreads();
    #pragma unroll
    for (int off = 1; off < 1024; off <<= 1) {
        const int x = (t >= off) ? buf[t - off] : 0;
        __syncthreads();
        buf[t] += x;
        __syncthreads();
    }
    if (t < NSB) bsum[t] = buf[t] - v;
    if (t == 1023) bsum[NSB] = buf[t];
}

__global__ __launch_bounds__(SCAN_B)
void scan_add(int* __restrict__ H, const int* __restrict__ bsum)
{
    const int g = blockIdx.x * SCAN_B + threadIdx.x;
    if (g < NS) H[g] += bsum[blockIdx.x];
}

__global__ __launch_bounds__(256)
void bucket_scatter(const int* __restrict__ src, const int* __restrict__ dst,
                    const int* __restrict__ S, int* __restrict__ EP)
{
    __shared__ int cur[NBUK];
    const int t = threadIdx.x;
    for (int i = t; i < NBUK; i += 256) cur[i] = S[i * NHB + blockIdx.x];
    __syncthreads();
    const int e0 = blockIdx.x * EPB;
    for (int i = t; i < EPB; i += 256) {
        const int e = e0 + i;
        if (e < NE) {
            const int s = src[e];
            const int pos = atomicAdd(&cur[s >> 6], 1);
            EP[pos] = ((s & 63) << 16) | dst[e];
        }
    }
}

// ---------------------------------------------------------------------------
// bucket_sort: one block per bucket. Counting-sort the bucket's EP segment by
// local node -> global CSR (offs, deg) + sorted ushort dst list (sdst).
// Two passes over global EP (L2-hot), no LDS edge staging -> no size limit.
// ---------------------------------------------------------------------------
__global__ __launch_bounds__(256)
void bucket_sort(const int* __restrict__ S, const int* __restrict__ EP,
                 unsigned short* __restrict__ sdst, int* __restrict__ offs,
                 int* __restrict__ deg)
{
    __shared__ int hist[NPB], cur[NPB], segBeg[NPB + 1];
    const int t = threadIdx.x;
    const int b = blockIdx.x;
    const int node0 = b * NPB;
    const int nNodes = min(NPB, NN - node0);
    const int beg = S[b * NHB];
    const int end = (b == NBUK - 1) ? NE : S[(b + 1) * NHB];

    if (t < NPB) hist[t] = 0;
    __syncthreads();
    for (int i = beg + t; i < end; i += 256) atomicAdd(&hist[EP[i] >> 16], 1);
    __syncthreads();
    if (t == 0) {
        int s = 0;
        for (int i = 0; i < NPB; ++i) { segBeg[i] = s; s += hist[i]; }
        segBeg[NPB] = s;
    }
    __syncthreads();
    if (t < nNodes) {
        offs[node0 + t] = beg + segBeg[t];
        deg[node0 + t] = hist[t];
    }
    if (b == NBUK - 1 && t == 0) offs[NN] = end;
    if (t < NPB) cur[t] = segBeg[t];
    __syncthreads();
    for (int i = beg + t; i < end; i += 256) {
        const int p = EP[i];
        const int pos = atomicAdd(&cur[p >> 16], 1);
        sdst[beg + pos] = (unsigned short)(p & 0xFFFF);
    }
}

// ---------------------------------------------------------------------------
// Lean gather: Y[n] = sum over sorted seg of X[dst]. No LDS, no atomics.
// Block 512 thr (8 waves) per bucket; wave handles 8 nodes sequentially.
// 16 lanes x 16B cover one 256B row; subgroup g = lane>>4 owns edge i+g.
// ---------------------------------------------------------------------------
__global__ __launch_bounds__(512)
void gather_lean(const int* __restrict__ offs, const unsigned short* __restrict__ sdst,
                 const unsigned short* __restrict__ X, unsigned short* __restrict__ Y)
{
    const int t = threadIdx.x;
    const int w = t >> 6;
    const int lane = t & 63;
    const int g = lane >> 4;            // 0..3
    const int cb = (lane & 15) * 8;     // channel base (bf16 units), 16B aligned
    const int node0 = blockIdx.x * NPB;

    for (int ni = 0; ni < 8; ++ni) {
        const int n = node0 + w * 8 + ni;
        if (n >= NN) break;
        const int sb = offs[n];
        const int se = offs[n + 1];
        float acc[8];
        #pragma unroll
        for (int j = 0; j < 8; ++j) acc[j] = 0.f;

        int i = sb;
        for (; i + 8 <= se; i += 8) {
            const int dA = sdst[i + g];
            const int dB = sdst[i + 4 + g];
            const uint4 vA = *reinterpret_cast<const uint4*>(&X[(size_t)dA * CH + cb]);
            const uint4 vB = *reinterpret_cast<const uint4*>(&X[(size_t)dB * CH + cb]);
            acc[0] += bflo(vA.x) + bflo(vB.x); acc[1] += bfhi(vA.x) + bfhi(vB.x);
            acc[2] += bflo(vA.y) + bflo(vB.y); acc[3] += bfhi(vA.y) + bfhi(vB.y);
            acc[4] += bflo(vA.z) + bflo(vB.z); acc[5] += bfhi(vA.z) + bfhi(vB.z);
            acc[6] += bflo(vA.w) + bflo(vB.w); acc[7] += bfhi(vA.w) + bfhi(vB.w);
        }
        if (i + 4 <= se) {
            const int d = sdst[i + g];
            const uint4 v = *reinterpret_cast<const uint4*>(&X[(size_t)d * CH + cb]);
            acc[0] += bflo(v.x); acc[1] += bfhi(v.x);
            acc[2] += bflo(v.y); acc[3] += bfhi(v.y);
            acc[4] += bflo(v.z); acc[5] += bfhi(v.z);
            acc[6] += bflo(v.w); acc[7] += bfhi(v.w);
            i += 4;
        }
        const int rem = se - i;          // 0..3
        if (g < rem) {
            const int d = sdst[i + g];
            const uint4 v = *reinterpret_cast<const uint4*>(&X[(size_t)d * CH + cb]);
            acc[0] += bflo(v.x); acc[1] += bfhi(v.x);
            acc[2] += bflo(v.y); acc[3] += bfhi(v.y);
            acc[4] += bflo(v.z); acc[5] += bfhi(v.z);
            acc[6] += bflo(v.w); acc[7] += bfhi(v.w);
        }

        #pragma unroll
        for (int j = 0; j < 8; ++j) {
            acc[j] += __shfl_xor(acc[j], 16);
            acc[j] += __shfl_xor(acc[j], 32);
        }

        if (lane < 16) {
            uint4 o;
            o.x = ((unsigned)f2bf(acc[1]) << 16) | f2bf(acc[0]);
            o.y = ((unsigned)f2bf(acc[3]) << 16) | f2bf(acc[2]);
            o.z = ((unsigned)f2bf(acc[5]) << 16) | f2bf(acc[4]);
            o.w = ((unsigned)f2bf(acc[7]) << 16) | f2bf(acc[6]);
            *reinterpret_cast<uint4*>(&Y[(size_t)n * CH + cb]) = o;
        }
    }
}

// ---------------------------------------------------------------------------
// small_prep: M = W2 @ Wfc (128x40), cfc = b2 @ Wfc (40). 20 blocks.
// ---------------------------------------------------------------------------
__global__ __launch_bounds__(256)
void small_prep(const float* __restrict__ W2, const float* __restrict__ Wfc,
                const float* __restrict__ b2, float* __restrict__ M,
                float* __restrict__ cfc)
{
    const int idx = blockIdx.x * 256 + threadIdx.x;
    if (idx < 128 * NCLS) {
        const int k = idx / NCLS;
        const int c = idx % NCLS;
        float a = 0.f;
        #pragma unroll 16
        for (int j = 0; j < 128; ++j) a += W2[k * 128 + j] * Wfc[j * NCLS + c];
        M[idx] = a;
    }
    if (blockIdx.x == 0 && threadIdx.x < NCLS) {
        const int c = threadIdx.x;
        float a = 0.f;
        #pragma unroll 16
        for (int j = 0; j < 128; ++j) a += b2[j] * Wfc[j * NCLS + c];
        cfc[c] = a;
    }
}

// ---------------------------------------------------------------------------
// out(N,40) = T(bf16) @ M + deg*cfc + bfc
// ---------------------------------------------------------------------------
__global__ __launch_bounds__(256)
void fc_tail(const unsigned short* __restrict__ T, const float* __restrict__ M,
             const float* __restrict__ cfc, const float* __restrict__ bfc,
             const int* __restrict__ deg, float* __restrict__ Y)
{
    __shared__ float Ml[128 * NCLS];  // 20 KB
    __shared__ float cl[NCLS], bl[NCLS];
    const int t = threadIdx.x;
    for (int i = t; i < 128 * NCLS; i += 256) Ml[i] = M[i];
    if (t < NCLS) { cl[t] = cfc[t]; bl[t] = bfc[t]; }
    __syncthreads();

    const int idx = blockIdx.x * 256 + t;
    if (idx >= NN * NCLS) return;
    const int row = idx / NCLS;
    const int c   = idx % NCLS;
    const unsigned* xr = reinterpret_cast<const unsigned*>(&T[(size_t)row * CH]);
    float acc = bl[c] + (float)deg[row] * cl[c];
    #pragma unroll 8
    for (int k = 0; k < 64; ++k) {
        const unsigned v = xr[k];
        acc += bflo(v) * Ml[(2 * k) * NCLS + c] + bfhi(v) * Ml[(2 * k + 1) * NCLS + c];
    }
    Y[idx] = acc;
}

extern "C" void kernel_launch(void* const* d_in, const int* in_sizes, int n_in,
                              void* d_out, int out_size, void* d_ws, size_t ws_size,
                              hipStream_t stream) {
    const float* F   = (const float*)d_in[0];  // (1,N,128)
    const int*   EI  = (const int*)  d_in[1];  // (1,2,E) int32
    const float* W1  = (const float*)d_in[3];
    const float* b1  = (const float*)d_in[4];
    const float* W2  = (const float*)d_in[5];
    const float* b2  = (const float*)d_in[6];
    const float* Wfc = (const float*)d_in[7];
    const float* bfc = (const float*)d_in[8];
    float* out = (float*)d_out;

    char* ws = (char*)d_ws;
    unsigned short* A = (unsigned short*)(ws);                 // bf16, 12.8 MB
    unsigned short* B = (unsigned short*)(ws + BF_BYTES);      // bf16, 12.8 MB
    int*   EP   = (int*)  (ws + 2 * BF_BYTES);                 // NE ints (6.4 MB)
    int*   H    = EP   + NE;                                   // NS ints
    int*   bsum = H    + NS;                                   // NSB+1
    int*   deg  = bsum + NSB + 1;                              // NN
    int*   offs = deg  + NN;                                   // NN+1
    unsigned short* sdst = (unsigned short*)(offs + NN + 1);   // NE ushort (3.2 MB)
    float* M    = (float*)(sdst + NE);                         // 128*40
    float* cfc  = M + 128 * NCLS;                              // 40

    const int* src = EI;          // edge_index[0,:]
    const int* dst = EI + NE;     // edge_index[1,:]

    // ---- bucket edges by src>>6, then per-bucket counting sort -> CSR ----
    bucket_hist<<<NHB, 256, 0, stream>>>(src, H);
    scan_local<<<NSB, SCAN_B, 0, stream>>>(H, bsum);
    scan_bsums<<<1, 1024, 0, stream>>>(bsum);
    scan_add<<<NSB, SCAN_B, 0, stream>>>(H, bsum);
    bucket_scatter<<<NHB, 256, 0, stream>>>(src, dst, H, EP);
    bucket_sort<<<NBUK, 256, 0, stream>>>(H, EP, sdst, offs, deg);

    // ---- tail-weight precompute ----
    small_prep<<<(128 * NCLS + 255) / 256, 256, 0, stream>>>(W2, Wfc, b2, M, cfc);

    // ---- H1 = relu(F @ W1 + b1) -> A (bf16, MFMA) ----
    gemm1_mfma<<<(NN + 63) / 64, 256, 0, stream>>>(F, W1, b1, A);

    // ---- S1 = gather-sum(A) -> B ----
    gather_lean<<<NBUK, 512, 0, stream>>>(offs, sdst, A, B);

    // ---- T = gather-sum(B) -> A ----
    gather_lean<<<NBUK, 512, 0, stream>>>(offs, sdst, B, A);

    // ---- out = T @ M + deg*cfc + bfc ----
    fc_tail<<<(NN * NCLS + 255) / 256, 256, 0, stream>>>(A, M, cfc, bfc, deg, out);
}

// Round 9
// 211.998 us; speedup vs baseline: 1.0159x; 1.0159x over previous
//
#include <hip/hip_runtime.h>

static constexpr int NN = 50000;    // nodes
static constexpr int NE = 1600000;  // edges
static constexpr int CH = 128;
static constexpr int NCLS = 40;
static constexpr size_t BF_BYTES = (size_t)NN * CH * 2;   // 12.8 MB bf16 matrix

static constexpr int NPB  = 256;                       // nodes per bucket
static constexpr int NBUK = (NN + NPB - 1) / NPB;      // 196
static constexpr int EPB  = 8192;                      // edges per hist block
static constexpr int NHB  = (NE + EPB - 1) / EPB;      // 196
static constexpr int NS   = NBUK * NHB;                // 38416 hist entries
static constexpr int SCAN_B = 256;
static constexpr int NSB  = (NS + SCAN_B - 1) / SCAN_B; // 151 (<=256)

typedef __attribute__((ext_vector_type(8))) short bf16x8;
typedef __attribute__((ext_vector_type(4))) float f32x4;

// ---- bf16 helpers (bit-level, RNE) ----
__device__ __forceinline__ float bflo(unsigned v) {
    return __uint_as_float((v & 0xFFFFu) << 16);
}
__device__ __forceinline__ float bfhi(unsigned v) {
    return __uint_as_float(v & 0xFFFF0000u);
}
__device__ __forceinline__ unsigned short f2bf(float f) {
    unsigned u = __float_as_uint(f);
    u += 0x7FFFu + ((u >> 16) & 1u);   // round to nearest even
    return (unsigned short)(u >> 16);
}

// ---------------------------------------------------------------------------
// H1 = relu(F @ W1 + b1) via bf16 MFMA. Block: 256 thr (4 waves), 64 rows.
// ---------------------------------------------------------------------------
__global__ __launch_bounds__(256)
void gemm1_mfma(const float* __restrict__ X, const float* __restrict__ W,
                const float* __restrict__ b, unsigned short* __restrict__ Y)
{
    constexpr int PAD = 136;
    __shared__ unsigned short Wt[128 * PAD];       // W1^T bf16 [c][k]
    __shared__ unsigned short Fa[64 * PAD];        // F tile bf16 [r][k]
    __shared__ float bl[128];

    const int t = threadIdx.x;
    const int lane = t & 63;
    const int w = t >> 6;

    {
        const int k = t >> 1;
        const int c0 = (t & 1) * 64;
        #pragma unroll 4
        for (int j = 0; j < 64; j += 4) {
            const float4 v = *reinterpret_cast<const float4*>(&W[k * 128 + c0 + j]);
            Wt[(c0 + j + 0) * PAD + k] = f2bf(v.x);
            Wt[(c0 + j + 1) * PAD + k] = f2bf(v.y);
            Wt[(c0 + j + 2) * PAD + k] = f2bf(v.z);
            Wt[(c0 + j + 3) * PAD + k] = f2bf(v.w);
        }
    }
    if (t < 128) bl[t] = b[t];

    const int base = blockIdx.x * 64;
    const int nRows = min(64, NN - base);
    {
        const int r = t >> 2;
        const int c0 = (t & 3) * 32;
        if (r < nRows) {
            #pragma unroll
            for (int j = 0; j < 32; j += 4) {
                const float4 v = *reinterpret_cast<const float4*>(&X[(size_t)(base + r) * CH + c0 + j]);
                ushort4 o; o.x = f2bf(v.x); o.y = f2bf(v.y); o.z = f2bf(v.z); o.w = f2bf(v.w);
                *reinterpret_cast<ushort4*>(&Fa[r * PAD + c0 + j]) = o;
            }
        } else {
            #pragma unroll
            for (int j = 0; j < 32; j += 4) {
                ushort4 z; z.x = z.y = z.z = z.w = 0;
                *reinterpret_cast<ushort4*>(&Fa[r * PAD + c0 + j]) = z;
            }
        }
    }
    __syncthreads();

    f32x4 acc[8];
    #pragma unroll
    for (int i = 0; i < 8; ++i) acc[i] = (f32x4){0.f, 0.f, 0.f, 0.f};

    const int arow = w * 16 + (lane & 15);
    const int kgrp = (lane >> 4) * 4;

    #pragma unroll
    for (int ks = 0; ks < 4; ++ks) {
        const int k0 = ks * 32 + kgrp;
        bf16x8 af;
        {
            const short4 lo = *reinterpret_cast<const short4*>(&Fa[arow * PAD + k0]);
            const short4 hi = *reinterpret_cast<const short4*>(&Fa[arow * PAD + k0 + 16]);
            af[0] = lo.x; af[1] = lo.y; af[2] = lo.z; af[3] = lo.w;
            af[4] = hi.x; af[5] = hi.y; af[6] = hi.z; af[7] = hi.w;
        }
        #pragma unroll
        for (int ct = 0; ct < 8; ++ct) {
            const int c = ct * 16 + (lane & 15);
            bf16x8 bf;
            const short4 lo = *reinterpret_cast<const short4*>(&Wt[c * PAD + k0]);
            const short4 hi = *reinterpret_cast<const short4*>(&Wt[c * PAD + k0 + 16]);
            bf[0] = lo.x; bf[1] = lo.y; bf[2] = lo.z; bf[3] = lo.w;
            bf[4] = hi.x; bf[5] = hi.y; bf[6] = hi.z; bf[7] = hi.w;
            acc[ct] = __builtin_amdgcn_mfma_f32_16x16x32_bf16(af, bf, acc[ct], 0, 0, 0);
        }
    }
    __syncthreads();

    #pragma unroll
    for (int ct = 0; ct < 8; ++ct) {
        const int c = ct * 16 + (lane & 15);
        const float bias = bl[c];
        #pragma unroll
        for (int r = 0; r < 4; ++r) {
            const int row = w * 16 + (lane >> 4) * 4 + r;
            Fa[row * PAD + c] = f2bf(fmaxf(acc[ct][r] + bias, 0.f));
        }
    }
    __syncthreads();

    {
        const int r = t >> 2;
        const int c0 = (t & 3) * 32;
        if (r < nRows) {
            #pragma unroll
            for (int j = 0; j < 32; j += 8) {
                const ulong2 v = *reinterpret_cast<const ulong2*>(&Fa[r * PAD + c0 + j]);
                *reinterpret_cast<ulong2*>(&Y[(size_t)(base + r) * CH + c0 + j]) = v;
            }
        }
    }
}

// ---------------------------------------------------------------------------
// Bucketing: per-block LDS histogram over 196 coarse buckets (src>>8)
// ---------------------------------------------------------------------------
__global__ __launch_bounds__(256)
void bucket_hist(const int* __restrict__ src, int* __restrict__ H)
{
    __shared__ int h[NBUK];
    const int t = threadIdx.x;
    for (int i = t; i < NBUK; i += 256) h[i] = 0;
    __syncthreads();
    const int e0 = blockIdx.x * EPB;
    for (int i = t; i < EPB; i += 256) {
        const int e = e0 + i;
        if (e < NE) atomicAdd(&h[src[e] >> 8], 1);
    }
    __syncthreads();
    for (int i = t; i < NBUK; i += 256) H[i * NHB + blockIdx.x] = h[i];
}

__global__ __launch_bounds__(SCAN_B)
void scan_local(int* __restrict__ H, int* __restrict__ bsum)
{
    __shared__ int buf[SCAN_B];
    const int t = threadIdx.x;
    const int g = blockIdx.x * SCAN_B + t;
    const int v = (g < NS) ? H[g] : 0;
    buf[t] = v;
    __syncthreads();
    #pragma unroll
    for (int off = 1; off < SCAN_B; off <<= 1) {
        const int x = (t >= off) ? buf[t - off] : 0;
        __syncthreads();
        buf[t] += x;
        __syncthreads();
    }
    if (g < NS) H[g] = buf[t] - v;
    if (t == SCAN_B - 1) bsum[blockIdx.x] = buf[t];
}

__global__ __launch_bounds__(SCAN_B)
void scan_bsums(int* __restrict__ bsum)
{
    __shared__ int buf[SCAN_B];
    const int t = threadIdx.x;
    const int v = (t < NSB) ? bsum[t] : 0;
    buf[t] = v;
    __syncthreads();
    #pragma unroll
    for (int off = 1; off < SCAN_B; off <<= 1) {
        const int x = (t >= off) ? buf[t - off] : 0;
        __syncthreads();
        buf[t] += x;
        __syncthreads();
    }
    if (t < NSB) bsum[t] = buf[t] - v;
    if (t == SCAN_B - 1) bsum[NSB] = buf[t];
}

__global__ __launch_bounds__(SCAN_B)
void scan_add(int* __restrict__ H, const int* __restrict__ bsum)
{
    const int g = blockIdx.x * SCAN_B + threadIdx.x;
    if (g < NS) H[g] += bsum[blockIdx.x];
}

// scatter packed edges ((src&255)<<16 | dst) into bucket-grouped EP
__global__ __launch_bounds__(256)
void bucket_scatter(const int* __restrict__ src, const int* __restrict__ dst,
                    const int* __restrict__ S, int* __restrict__ EP)
{
    __shared__ int cur[NBUK];
    const int t = threadIdx.x;
    for (int i = t; i < NBUK; i += 256) cur[i] = S[i * NHB + blockIdx.x];
    __syncthreads();
    const int e0 = blockIdx.x * EPB;
    for (int i = t; i < EPB; i += 256) {
        const int e = e0 + i;
        if (e < NE) {
            const int s = src[e];
            const int pos = atomicAdd(&cur[s >> 8], 1);
            EP[pos] = ((s & 255) << 16) | dst[e];
        }
    }
}

// ---------------------------------------------------------------------------
// bucket_sort: one 512-thr block per bucket (256 nodes). Counting-sort the
// bucket's EP segment by local node -> CSR (offs, deg) + sorted ushort dsts.
// ---------------------------------------------------------------------------
__global__ __launch_bounds__(512)
void bucket_sort(const int* __restrict__ S, const int* __restrict__ EP,
                 unsigned short* __restrict__ sdst, int* __restrict__ offs,
                 int* __restrict__ deg)
{
    __shared__ int hist[NPB], cur[NPB], segBeg[NPB + 1], buf[NPB];
    const int t = threadIdx.x;
    const int b = blockIdx.x;
    const int node0 = b * NPB;
    const int nNodes = min(NPB, NN - node0);
    const int beg = S[b * NHB];
    const int end = (b == NBUK - 1) ? NE : S[(b + 1) * NHB];

    if (t < NPB) hist[t] = 0;
    __syncthreads();
    for (int i = beg + t; i < end; i += 512) atomicAdd(&hist[EP[i] >> 16], 1);
    __syncthreads();

    // parallel exclusive scan of hist[256]
    if (t < NPB) buf[t] = hist[t];
    __syncthreads();
    #pragma unroll
    for (int off = 1; off < NPB; off <<= 1) {
        int x = 0;
        if (t < NPB && t >= off) x = buf[t - off];
        __syncthreads();
        if (t < NPB) buf[t] += x;
        __syncthreads();
    }
    if (t < NPB) segBeg[t] = buf[t] - hist[t];
    if (t == 0) segBeg[NPB] = end - beg;
    __syncthreads();

    if (t < nNodes) {
        offs[node0 + t] = beg + segBeg[t];
        deg[node0 + t] = hist[t];
    }
    if (b == NBUK - 1 && t == 0) offs[NN] = end;
    if (t < NPB) cur[t] = segBeg[t];
    __syncthreads();
    for (int i = beg + t; i < end; i += 512) {
        const int p = EP[i];
        const int pos = atomicAdd(&cur[p >> 16], 1);
        sdst[beg + pos] = (unsigned short)(p & 0xFFFF);
    }
}

// ---------------------------------------------------------------------------
// Lean gather: Y[n] = sum over sorted seg of X[dst]. No LDS, no atomics.
// Block 512 thr (8 waves), 4 nodes per wave -> 32 nodes/block, 1563 blocks.
// 16 lanes x 16B cover one 256B row; subgroup g = lane>>4 owns edge i+g.
// ---------------------------------------------------------------------------
__global__ __launch_bounds__(512)
void gather_lean(const int* __restrict__ offs, const unsigned short* __restrict__ sdst,
                 const unsigned short* __restrict__ X, unsigned short* __restrict__ Y)
{
    const int t = threadIdx.x;
    const int w = t >> 6;
    const int lane = t & 63;
    const int g = lane >> 4;            // 0..3
    const int cb = (lane & 15) * 8;     // channel base (bf16 units), 16B aligned
    const int node0 = blockIdx.x * 32 + w * 4;

    #pragma unroll
    for (int ni = 0; ni < 4; ++ni) {
        const int n = node0 + ni;
        if (n >= NN) break;
        const int sb = offs[n];
        const int se = offs[n + 1];
        float acc[8];
        #pragma unroll
        for (int j = 0; j < 8; ++j) acc[j] = 0.f;

        int i = sb;
        for (; i + 8 <= se; i += 8) {
            const int dA = sdst[i + g];
            const int dB = sdst[i + 4 + g];
            const uint4 vA = *reinterpret_cast<const uint4*>(&X[(size_t)dA * CH + cb]);
            const uint4 vB = *reinterpret_cast<const uint4*>(&X[(size_t)dB * CH + cb]);
            acc[0] += bflo(vA.x) + bflo(vB.x); acc[1] += bfhi(vA.x) + bfhi(vB.x);
            acc[2] += bflo(vA.y) + bflo(vB.y); acc[3] += bfhi(vA.y) + bfhi(vB.y);
            acc[4] += bflo(vA.z) + bflo(vB.z); acc[5] += bfhi(vA.z) + bfhi(vB.z);
            acc[6] += bflo(vA.w) + bflo(vB.w); acc[7] += bfhi(vA.w) + bfhi(vB.w);
        }
        if (i + 4 <= se) {
            const int d = sdst[i + g];
            const uint4 v = *reinterpret_cast<const uint4*>(&X[(size_t)d * CH + cb]);
            acc[0] += bflo(v.x); acc[1] += bfhi(v.x);
            acc[2] += bflo(v.y); acc[3] += bfhi(v.y);
            acc[4] += bflo(v.z); acc[5] += bfhi(v.z);
            acc[6] += bflo(v.w); acc[7] += bfhi(v.w);
            i += 4;
        }
        const int rem = se - i;          // 0..3
        if (g < rem) {
            const int d = sdst[i + g];
            const uint4 v = *reinterpret_cast<const uint4*>(&X[(size_t)d * CH + cb]);
            acc[0] += bflo(v.x); acc[1] += bfhi(v.x);
            acc[2] += bflo(v.y); acc[3] += bfhi(v.y);
            acc[4] += bflo(v.z); acc[5] += bfhi(v.z);
            acc[6] += bflo(v.w); acc[7] += bfhi(v.w);
        }

        #pragma unroll
        for (int j = 0; j < 8; ++j) {
            acc[j] += __shfl_xor(acc[j], 16);
            acc[j] += __shfl_xor(acc[j], 32);
        }

        if (lane < 16) {
            uint4 o;
            o.x = ((unsigned)f2bf(acc[1]) << 16) | f2bf(acc[0]);
            o.y = ((unsigned)f2bf(acc[3]) << 16) | f2bf(acc[2]);
            o.z = ((unsigned)f2bf(acc[5]) << 16) | f2bf(acc[4]);
            o.w = ((unsigned)f2bf(acc[7]) << 16) | f2bf(acc[6]);
            *reinterpret_cast<uint4*>(&Y[(size_t)n * CH + cb]) = o;
        }
    }
}

// ---------------------------------------------------------------------------
// small_prep: M = W2 @ Wfc (128x40), cfc = b2 @ Wfc (40). 20 blocks.
// ---------------------------------------------------------------------------
__global__ __launch_bounds__(256)
void small_prep(const float* __restrict__ W2, const float* __restrict__ Wfc,
                const float* __restrict__ b2, float* __restrict__ M,
                float* __restrict__ cfc)
{
    const int idx = blockIdx.x * 256 + threadIdx.x;
    if (idx < 128 * NCLS) {
        const int k = idx / NCLS;
        const int c = idx % NCLS;
        float a = 0.f;
        #pragma unroll 16
        for (int j = 0; j < 128; ++j) a += W2[k * 128 + j] * Wfc[j * NCLS + c];
        M[idx] = a;
    }
    if (blockIdx.x == 0 && threadIdx.x < NCLS) {
        const int c = threadIdx.x;
        float a = 0.f;
        #pragma unroll 16
        for (int j = 0; j < 128; ++j) a += b2[j] * Wfc[j * NCLS + c];
        cfc[c] = a;
    }
}

// ---------------------------------------------------------------------------
// out(N,40) = T(bf16) @ M + deg*cfc + bfc
// ---------------------------------------------------------------------------
__global__ __launch_bounds__(256)
void fc_tail(const unsigned short* __restrict__ T, const float* __restrict__ M,
             const float* __restrict__ cfc, const float* __restrict__ bfc,
             const int* __restrict__ deg, float* __restrict__ Y)
{
    __shared__ float Ml[128 * NCLS];  // 20 KB
    __shared__ float cl[NCLS], bl[NCLS];
    const int t = threadIdx.x;
    for (int i = t; i < 128 * NCLS; i += 256) Ml[i] = M[i];
    if (t < NCLS) { cl[t] = cfc[t]; bl[t] = bfc[t]; }
    __syncthreads();

    const int idx = blockIdx.x * 256 + t;
    if (idx >= NN * NCLS) return;
    const int row = idx / NCLS;
    const int c   = idx % NCLS;
    const unsigned* xr = reinterpret_cast<const unsigned*>(&T[(size_t)row * CH]);
    float acc = bl[c] + (float)deg[row] * cl[c];
    #pragma unroll 8
    for (int k = 0; k < 64; ++k) {
        const unsigned v = xr[k];
        acc += bflo(v) * Ml[(2 * k) * NCLS + c] + bfhi(v) * Ml[(2 * k + 1) * NCLS + c];
    }
    Y[idx] = acc;
}

extern "C" void kernel_launch(void* const* d_in, const int* in_sizes, int n_in,
                              void* d_out, int out_size, void* d_ws, size_t ws_size,
                              hipStream_t stream) {
    const float* F   = (const float*)d_in[0];  // (1,N,128)
    const int*   EI  = (const int*)  d_in[1];  // (1,2,E) int32
    const float* W1  = (const float*)d_in[3];
    const float* b1  = (const float*)d_in[4];
    const float* W2  = (const float*)d_in[5];
    const float* b2  = (const float*)d_in[6];
    const float* Wfc = (const float*)d_in[7];
    const float* bfc = (const float*)d_in[8];
    float* out = (float*)d_out;

    char* ws = (char*)d_ws;
    unsigned short* A = (unsigned short*)(ws);                 // bf16, 12.8 MB
    unsigned short* B = (unsigned short*)(ws + BF_BYTES);      // bf16, 12.8 MB
    int*   EP   = (int*)  (ws + 2 * BF_BYTES);                 // NE ints (6.4 MB)
    int*   H    = EP   + NE;                                   // NS ints
    int*   bsum = H    + NS;                                   // NSB+1
    int*   deg  = bsum + NSB + 1;                              // NN
    int*   offs = deg  + NN;                                   // NN+1
    unsigned short* sdst = (unsigned short*)(offs + NN + 1);   // NE ushort (3.2 MB)
    float* M    = (float*)(sdst + NE);                         // 128*40
    float* cfc  = M + 128 * NCLS;                              // 40

    const int* src = EI;          // edge_index[0,:]
    const int* dst = EI + NE;     // edge_index[1,:]

    // ---- bucket edges by src>>8, then per-bucket counting sort -> CSR ----
    bucket_hist<<<NHB, 256, 0, stream>>>(src, H);
    scan_local<<<NSB, SCAN_B, 0, stream>>>(H, bsum);
    scan_bsums<<<1, SCAN_B, 0, stream>>>(bsum);
    scan_add<<<NSB, SCAN_B, 0, stream>>>(H, bsum);
    bucket_scatter<<<NHB, 256, 0, stream>>>(src, dst, H, EP);
    bucket_sort<<<NBUK, 512, 0, stream>>>(H, EP, sdst, offs, deg);

    // ---- tail-weight precompute ----
    small_prep<<<(128 * NCLS + 255) / 256, 256, 0, stream>>>(W2, Wfc, b2, M, cfc);

    // ---- H1 = relu(F @ W1 + b1) -> A (bf16, MFMA) ----
    gemm1_mfma<<<(NN + 63) / 64, 256, 0, stream>>>(F, W1, b1, A);

    // ---- S1 = gather-sum(A) -> B ----
    gather_lean<<<(NN + 31) / 32, 512, 0, stream>>>(offs, sdst, A, B);

    // ---- T = gather-sum(B) -> A ----
    gather_lean<<<(NN + 31) / 32, 512, 0, stream>>>(offs, sdst, B, A);

    // ---- out = T @ M + deg*cfc + bfc ----
    fc_tail<<<(NN * NCLS + 255) / 256, 256, 0, stream>>>(A, M, cfc, bfc, deg, out);
}

// Round 11
// 165.667 us; speedup vs baseline: 1.3000x; 1.2797x over previous
//
#include <hip/hip_runtime.h>

static constexpr int NN = 50000;    // nodes
static constexpr int NE = 1600000;  // edges
static constexpr int CH = 128;
static constexpr int NCLS = 40;

static constexpr int NPB  = 256;                       // nodes per bucket
static constexpr int NBUK = (NN + NPB - 1) / NPB;      // 196
static constexpr int EPB  = 8192;                      // edges per hist block
static constexpr int NHB  = (NE + EPB - 1) / EPB;      // 196
static constexpr int NS   = NBUK * NHB;                // 38416 hist entries
static constexpr int SCAN_B = 256;
static constexpr int NSB  = (NS + SCAN_B - 1) / SCAN_B; // 151 (<=256)
static constexpr int NROWP = ((NN + 63) / 64) * 64;    // 50048 padded V1 rows

typedef __attribute__((ext_vector_type(8))) short bf16x8;
typedef __attribute__((ext_vector_type(4))) float f32x4;

// ---- bf16 helpers (bit-level, RNE) ----
__device__ __forceinline__ float bflo(unsigned v) {
    return __uint_as_float((v & 0xFFFFu) << 16);
}
__device__ __forceinline__ float bfhi(unsigned v) {
    return __uint_as_float(v & 0xFFFF0000u);
}
__device__ __forceinline__ unsigned short f2bf(float f) {
    unsigned u = __float_as_uint(f);
    u += 0x7FFFu + ((u >> 16) & 1u);   // round to nearest even
    return (unsigned short)(u >> 16);
}

// ---------------------------------------------------------------------------
// small_prep2: Mt[c][k] = (W2@Wfc)^T bf16, 48x128 (c>=40 zero); cfc = b2@Wfc.
// ---------------------------------------------------------------------------
__global__ __launch_bounds__(256)
void small_prep2(const float* __restrict__ W2, const float* __restrict__ Wfc,
                 const float* __restrict__ b2, unsigned short* __restrict__ Mt,
                 float* __restrict__ cfc)
{
    const int idx = blockIdx.x * 256 + threadIdx.x;   // 0..6143
    if (idx < 48 * 128) {
        const int c = idx >> 7;
        const int k = idx & 127;
        float a = 0.f;
        if (c < NCLS) {
            #pragma unroll 16
            for (int j = 0; j < 128; ++j) a += W2[k * 128 + j] * Wfc[j * NCLS + c];
        }
        Mt[c * 128 + k] = f2bf(a);
    }
    if (blockIdx.x == 0 && threadIdx.x < NCLS) {
        const int c = threadIdx.x;
        float a = 0.f;
        #pragma unroll 16
        for (int j = 0; j < 128; ++j) a += b2[j] * Wfc[j * NCLS + c];
        cfc[c] = a;
    }
}

// ---------------------------------------------------------------------------
// gemm1v: V1 = relu(F @ W1 + b1) @ Mb  (fused two-stage MFMA, V1 bf16 40-wide)
// Block: 256 thr (4 waves), 64 rows. Stage1: 8 col-tiles x 4 k-steps.
// Stage2: H1 tile via LDS, B-frags from global Mt (12 KB, L1-hot), 3 col-tiles.
// ---------------------------------------------------------------------------
__global__ __launch_bounds__(256)
void gemm1v(const float* __restrict__ X, const float* __restrict__ W,
            const float* __restrict__ b, const unsigned short* __restrict__ Mt,
            unsigned short* __restrict__ V1)
{
    constexpr int PAD = 136;
    __shared__ __align__(16) unsigned short Wt[128 * PAD];   // W1^T bf16 [c][k]
    __shared__ __align__(16) unsigned short Fa[64 * PAD];    // F tile, then H1 tile
    __shared__ __align__(16) unsigned short Va[64 * NCLS];   // V1 staging (5 KB)
    __shared__ float bl[128];

    const int t = threadIdx.x;
    const int lane = t & 63;
    const int w = t >> 6;

    // ---- stage Wt = W1^T (bf16) ----
    {
        const int k = t >> 1;
        const int c0 = (t & 1) * 64;
        #pragma unroll 4
        for (int j = 0; j < 64; j += 4) {
            const float4 v = *reinterpret_cast<const float4*>(&W[k * 128 + c0 + j]);
            Wt[(c0 + j + 0) * PAD + k] = f2bf(v.x);
            Wt[(c0 + j + 1) * PAD + k] = f2bf(v.y);
            Wt[(c0 + j + 2) * PAD + k] = f2bf(v.z);
            Wt[(c0 + j + 3) * PAD + k] = f2bf(v.w);
        }
    }
    if (t < 128) bl[t] = b[t];

    // ---- stage Fa (f32 -> bf16) ----
    const int base = blockIdx.x * 64;
    const int nRows = min(64, NN - base);
    {
        const int r = t >> 2;
        const int c0 = (t & 3) * 32;
        if (r < nRows) {
            #pragma unroll
            for (int j = 0; j < 32; j += 4) {
                const float4 v = *reinterpret_cast<const float4*>(&X[(size_t)(base + r) * CH + c0 + j]);
                ushort4 o; o.x = f2bf(v.x); o.y = f2bf(v.y); o.z = f2bf(v.z); o.w = f2bf(v.w);
                *reinterpret_cast<ushort4*>(&Fa[r * PAD + c0 + j]) = o;
            }
        } else {
            #pragma unroll
            for (int j = 0; j < 32; j += 4) {
                ushort4 z; z.x = z.y = z.z = z.w = 0;
                *reinterpret_cast<ushort4*>(&Fa[r * PAD + c0 + j]) = z;
            }
        }
    }
    __syncthreads();

    // ---- stage 1 MFMA: H1 = relu(F@W1+b1) ----
    f32x4 acc[8];
    #pragma unroll
    for (int i = 0; i < 8; ++i) acc[i] = (f32x4){0.f, 0.f, 0.f, 0.f};

    const int arow = w * 16 + (lane & 15);
    const int kgrp = (lane >> 4) * 4;

    #pragma unroll
    for (int ks = 0; ks < 4; ++ks) {
        const int k0 = ks * 32 + kgrp;
        bf16x8 af;
        {
            const short4 lo = *reinterpret_cast<const short4*>(&Fa[arow * PAD + k0]);
            const short4 hi = *reinterpret_cast<const short4*>(&Fa[arow * PAD + k0 + 16]);
            af[0] = lo.x; af[1] = lo.y; af[2] = lo.z; af[3] = lo.w;
            af[4] = hi.x; af[5] = hi.y; af[6] = hi.z; af[7] = hi.w;
        }
        #pragma unroll
        for (int ct = 0; ct < 8; ++ct) {
            const int c = ct * 16 + (lane & 15);
            bf16x8 bf;
            const short4 lo = *reinterpret_cast<const short4*>(&Wt[c * PAD + k0]);
            const short4 hi = *reinterpret_cast<const short4*>(&Wt[c * PAD + k0 + 16]);
            bf[0] = lo.x; bf[1] = lo.y; bf[2] = lo.z; bf[3] = lo.w;
            bf[4] = hi.x; bf[5] = hi.y; bf[6] = hi.z; bf[7] = hi.w;
            acc[ct] = __builtin_amdgcn_mfma_f32_16x16x32_bf16(af, bf, acc[ct], 0, 0, 0);
        }
    }
    __syncthreads();   // Fa (F tile) consumed

    // ---- bias + relu -> H1 tile (bf16) into Fa ----
    #pragma unroll
    for (int ct = 0; ct < 8; ++ct) {
        const int c = ct * 16 + (lane & 15);
        const float bias = bl[c];
        #pragma unroll
        for (int r = 0; r < 4; ++r) {
            const int row = w * 16 + (lane >> 4) * 4 + r;
            Fa[row * PAD + c] = f2bf(fmaxf(acc[ct][r] + bias, 0.f));
        }
    }
    __syncthreads();

    // ---- stage 2 MFMA: V1 = H1 @ Mb (3 col-tiles, cols 0..47) ----
    f32x4 acc2[3];
    #pragma unroll
    for (int i = 0; i < 3; ++i) acc2[i] = (f32x4){0.f, 0.f, 0.f, 0.f};

    #pragma unroll
    for (int ks = 0; ks < 4; ++ks) {
        const int k0 = ks * 32 + kgrp;
        bf16x8 af;
        {
            const short4 lo = *reinterpret_cast<const short4*>(&Fa[arow * PAD + k0]);
            const short4 hi = *reinterpret_cast<const short4*>(&Fa[arow * PAD + k0 + 16]);
            af[0] = lo.x; af[1] = lo.y; af[2] = lo.z; af[3] = lo.w;
            af[4] = hi.x; af[5] = hi.y; af[6] = hi.z; af[7] = hi.w;
        }
        #pragma unroll
        for (int ct = 0; ct < 3; ++ct) {
            const int c = ct * 16 + (lane & 15);
            bf16x8 bf;
            const short4 lo = *reinterpret_cast<const short4*>(&Mt[c * 128 + k0]);
            const short4 hi = *reinterpret_cast<const short4*>(&Mt[c * 128 + k0 + 16]);
            bf[0] = lo.x; bf[1] = lo.y; bf[2] = lo.z; bf[3] = lo.w;
            bf[4] = hi.x; bf[5] = hi.y; bf[6] = hi.z; bf[7] = hi.w;
            acc2[ct] = __builtin_amdgcn_mfma_f32_16x16x32_bf16(af, bf, acc2[ct], 0, 0, 0);
        }
    }

    // ---- stash V1 tile (cols<40) into Va, then coalesced write ----
    #pragma unroll
    for (int ct = 0; ct < 3; ++ct) {
        const int c = ct * 16 + (lane & 15);
        if (c < NCLS) {
            #pragma unroll
            for (int r = 0; r < 4; ++r) {
                const int row = w * 16 + (lane >> 4) * 4 + r;
                Va[row * NCLS + c] = f2bf(acc2[ct][r]);
            }
        }
    }
    __syncthreads();

    // 64 rows x 80 B = 320 uint4 slots, 256 threads -> loop (BUG FIX vs r10:
    // "if (t < 320)" silently dropped rows 52..63 with a 256-thread block)
    for (int i = t; i < 320; i += 256) {
        const int r = i / 5;
        const int q = i % 5;
        *reinterpret_cast<uint4*>(&V1[(size_t)(base + r) * NCLS + q * 8]) =
            *reinterpret_cast<const uint4*>(&Va[r * NCLS + q * 8]);
    }
}

// ---------------------------------------------------------------------------
// Bucketing: per-block LDS histogram over 196 coarse buckets (src>>8)
// ---------------------------------------------------------------------------
__global__ __launch_bounds__(256)
void bucket_hist(const int* __restrict__ src, int* __restrict__ H)
{
    __shared__ int h[NBUK];
    const int t = threadIdx.x;
    for (int i = t; i < NBUK; i += 256) h[i] = 0;
    __syncthreads();
    const int e0 = blockIdx.x * EPB;
    for (int i = t; i < EPB; i += 256) {
        const int e = e0 + i;
        if (e < NE) atomicAdd(&h[src[e] >> 8], 1);
    }
    __syncthreads();
    for (int i = t; i < NBUK; i += 256) H[i * NHB + blockIdx.x] = h[i];
}

__global__ __launch_bounds__(SCAN_B)
void scan_local(int* __restrict__ H, int* __restrict__ bsum)
{
    __shared__ int buf[SCAN_B];
    const int t = threadIdx.x;
    const int g = blockIdx.x * SCAN_B + t;
    const int v = (g < NS) ? H[g] : 0;
    buf[t] = v;
    __syncthreads();
    #pragma unroll
    for (int off = 1; off < SCAN_B; off <<= 1) {
        const int x = (t >= off) ? buf[t - off] : 0;
        __syncthreads();
        buf[t] += x;
        __syncthreads();
    }
    if (g < NS) H[g] = buf[t] - v;
    if (t == SCAN_B - 1) bsum[blockIdx.x] = buf[t];
}

__global__ __launch_bounds__(SCAN_B)
void scan_bsums(int* __restrict__ bsum)
{
    __shared__ int buf[SCAN_B];
    const int t = threadIdx.x;
    const int v = (t < NSB) ? bsum[t] : 0;
    buf[t] = v;
    __syncthreads();
    #pragma unroll
    for (int off = 1; off < SCAN_B; off <<= 1) {
        const int x = (t >= off) ? buf[t - off] : 0;
        __syncthreads();
        buf[t] += x;
        __syncthreads();
    }
    if (t < NSB) bsum[t] = buf[t] - v;
    if (t == SCAN_B - 1) bsum[NSB] = buf[t];
}

__global__ __launch_bounds__(SCAN_B)
void scan_add(int* __restrict__ H, const int* __restrict__ bsum)
{
    const int g = blockIdx.x * SCAN_B + threadIdx.x;
    if (g < NS) H[g] += bsum[blockIdx.x];
}

// scatter packed edges ((src&255)<<16 | dst) into bucket-grouped EP
__global__ __launch_bounds__(256)
void bucket_scatter(const int* __restrict__ src, const int* __restrict__ dst,
                    const int* __restrict__ S, int* __restrict__ EP)
{
    __shared__ int cur[NBUK];
    const int t = threadIdx.x;
    for (int i = t; i < NBUK; i += 256) cur[i] = S[i * NHB + blockIdx.x];
    __syncthreads();
    const int e0 = blockIdx.x * EPB;
    for (int i = t; i < EPB; i += 256) {
        const int e = e0 + i;
        if (e < NE) {
            const int s = src[e];
            const int pos = atomicAdd(&cur[s >> 8], 1);
            EP[pos] = ((s & 255) << 16) | dst[e];
        }
    }
}

// ---------------------------------------------------------------------------
// bucket_sort: one 512-thr block per bucket (256 nodes). Counting-sort the
// bucket's EP segment by local node -> CSR (offs, deg) + sorted ushort dsts.
// ---------------------------------------------------------------------------
__global__ __launch_bounds__(512)
void bucket_sort(const int* __restrict__ S, const int* __restrict__ EP,
                 unsigned short* __restrict__ sdst, int* __restrict__ offs,
                 int* __restrict__ deg)
{
    __shared__ int hist[NPB], cur[NPB], segBeg[NPB + 1], buf[NPB];
    const int t = threadIdx.x;
    const int b = blockIdx.x;
    const int node0 = b * NPB;
    const int nNodes = min(NPB, NN - node0);
    const int beg = S[b * NHB];
    const int end = (b == NBUK - 1) ? NE : S[(b + 1) * NHB];

    if (t < NPB) hist[t] = 0;
    __syncthreads();
    for (int i = beg + t; i < end; i += 512) atomicAdd(&hist[EP[i] >> 16], 1);
    __syncthreads();

    if (t < NPB) buf[t] = hist[t];
    __syncthreads();
    #pragma unroll
    for (int off = 1; off < NPB; off <<= 1) {
        int x = 0;
        if (t < NPB && t >= off) x = buf[t - off];
        __syncthreads();
        if (t < NPB) buf[t] += x;
        __syncthreads();
    }
    if (t < NPB) segBeg[t] = buf[t] - hist[t];
    if (t == 0) segBeg[NPB] = end - beg;
    __syncthreads();

    if (t < nNodes) {
        offs[node0 + t] = beg + segBeg[t];
        deg[node0 + t] = hist[t];
    }
    if (b == NBUK - 1 && t == 0) offs[NN] = end;
    if (t < NPB) cur[t] = segBeg[t];
    __syncthreads();
    for (int i = beg + t; i < end; i += 512) {
        const int p = EP[i];
        const int pos = atomicAdd(&cur[p >> 16], 1);
        sdst[beg + pos] = (unsigned short)(p & 0xFFFF);
    }
}

// ---------------------------------------------------------------------------
// gather40: Y[n] = sum over seg of X[dst] (40-ch bf16 rows, 80 B).
// Block 512 thr (8 waves), 4 nodes per wave. Subgroup = 16 lanes per edge;
// lane L<10 loads uint2 (4 bf16, channels 4L..4L+3).
// FINAL: out f32 + deg*cfc + bfc.  else: bf16 U1.
// ---------------------------------------------------------------------------
template<bool FINAL>
__global__ __launch_bounds__(512)
void gather40(const int* __restrict__ offs, const unsigned short* __restrict__ sdst,
              const unsigned short* __restrict__ X,
              unsigned short* __restrict__ Yb, float* __restrict__ Yf,
              const int* __restrict__ deg,
              const float* __restrict__ cfc, const float* __restrict__ bfc)
{
    const int t = threadIdx.x;
    const int w = t >> 6;
    const int lane = t & 63;
    const int g = lane >> 4;            // 0..3: edge-in-flight slot
    const int L = lane & 15;            // channel-group lane
    const int node0 = blockIdx.x * 32 + w * 4;

    float4 cf = make_float4(0.f, 0.f, 0.f, 0.f);
    float4 bfv = make_float4(0.f, 0.f, 0.f, 0.f);
    if (FINAL && L < 10) {
        cf  = *reinterpret_cast<const float4*>(&cfc[L * 4]);
        bfv = *reinterpret_cast<const float4*>(&bfc[L * 4]);
    }

    #pragma unroll
    for (int ni = 0; ni < 4; ++ni) {
        const int n = node0 + ni;
        if (n >= NN) break;
        const int sb = offs[n];
        const int se = offs[n + 1];
        float a0 = 0.f, a1 = 0.f, a2 = 0.f, a3 = 0.f;

        int i = sb;
        for (; i + 8 <= se; i += 8) {
            const int dA = sdst[i + g];
            const int dB = sdst[i + 4 + g];
            if (L < 10) {
                const uint2 vA = *reinterpret_cast<const uint2*>(&X[(size_t)dA * NCLS + L * 4]);
                const uint2 vB = *reinterpret_cast<const uint2*>(&X[(size_t)dB * NCLS + L * 4]);
                a0 += bflo(vA.x) + bflo(vB.x); a1 += bfhi(vA.x) + bfhi(vB.x);
                a2 += bflo(vA.y) + bflo(vB.y); a3 += bfhi(vA.y) + bfhi(vB.y);
            }
        }
        if (i + 4 <= se) {
            const int d = sdst[i + g];
            if (L < 10) {
                const uint2 v = *reinterpret_cast<const uint2*>(&X[(size_t)d * NCLS + L * 4]);
                a0 += bflo(v.x); a1 += bfhi(v.x);
                a2 += bflo(v.y); a3 += bfhi(v.y);
            }
            i += 4;
        }
        const int rem = se - i;          // 0..3
        if (g < rem) {
            const int d = sdst[i + g];
            if (L < 10) {
                const uint2 v = *reinterpret_cast<const uint2*>(&X[(size_t)d * NCLS + L * 4]);
                a0 += bflo(v.x); a1 += bfhi(v.x);
                a2 += bflo(v.y); a3 += bfhi(v.y);
            }
        }

        a0 += __shfl_xor(a0, 16); a0 += __shfl_xor(a0, 32);
        a1 += __shfl_xor(a1, 16); a1 += __shfl_xor(a1, 32);
        a2 += __shfl_xor(a2, 16); a2 += __shfl_xor(a2, 32);
        a3 += __shfl_xor(a3, 16); a3 += __shfl_xor(a3, 32);

        if (lane < 16 && L < 10) {
            if (FINAL) {
                const float dgn = (float)deg[n];
                float4 o;
                o.x = a0 + dgn * cf.x + bfv.x;
                o.y = a1 + dgn * cf.y + bfv.y;
                o.z = a2 + dgn * cf.z + bfv.z;
                o.w = a3 + dgn * cf.w + bfv.w;
                *reinterpret_cast<float4*>(&Yf[(size_t)n * NCLS + L * 4]) = o;
            } else {
                uint2 o;
                o.x = ((unsigned)f2bf(a1) << 16) | f2bf(a0);
                o.y = ((unsigned)f2bf(a3) << 16) | f2bf(a2);
                *reinterpret_cast<uint2*>(&Yb[(size_t)n * NCLS + L * 4]) = o;
            }
        }
    }
}

extern "C" void kernel_launch(void* const* d_in, const int* in_sizes, int n_in,
                              void* d_out, int out_size, void* d_ws, size_t ws_size,
                              hipStream_t stream) {
    const float* F   = (const float*)d_in[0];  // (1,N,128)
    const int*   EI  = (const int*)  d_in[1];  // (1,2,E) int32
    const float* W1  = (const float*)d_in[3];
    const float* b1  = (const float*)d_in[4];
    const float* W2  = (const float*)d_in[5];
    const float* b2  = (const float*)d_in[6];
    const float* Wfc = (const float*)d_in[7];
    const float* bfc = (const float*)d_in[8];
    float* out = (float*)d_out;

    char* ws = (char*)d_ws;
    size_t off = 0;
    auto take = [&](size_t bytes) { char* p = ws + off; off += (bytes + 15) & ~(size_t)15; return p; };

    unsigned short* V1   = (unsigned short*)take((size_t)NROWP * NCLS * 2); // 4.0 MB
    unsigned short* U1   = (unsigned short*)take((size_t)NN * NCLS * 2);    // 4.0 MB
    unsigned short* sdst = (unsigned short*)take((size_t)NE * 2);           // 3.2 MB
    int*   EP   = (int*)take((size_t)NE * 4);                               // 6.4 MB
    int*   H    = (int*)take((size_t)NS * 4);
    int*   bsum = (int*)take((size_t)(NSB + 1) * 4);
    int*   deg  = (int*)take((size_t)NN * 4);
    int*   offs = (int*)take((size_t)(NN + 1) * 4);
    unsigned short* Mt = (unsigned short*)take((size_t)48 * 128 * 2);       // 12 KB
    float* cfc  = (float*)take((size_t)NCLS * 4);

    const int* src = EI;          // edge_index[0,:]
    const int* dst = EI + NE;     // edge_index[1,:]

    // ---- bucket edges by src>>8, then per-bucket counting sort -> CSR ----
    bucket_hist<<<NHB, 256, 0, stream>>>(src, H);
    scan_local<<<NSB, SCAN_B, 0, stream>>>(H, bsum);
    scan_bsums<<<1, SCAN_B, 0, stream>>>(bsum);
    scan_add<<<NSB, SCAN_B, 0, stream>>>(H, bsum);
    bucket_scatter<<<NHB, 256, 0, stream>>>(src, dst, H, EP);
    bucket_sort<<<NBUK, 512, 0, stream>>>(H, EP, sdst, offs, deg);

    // ---- tail-weight precompute: Mt = (W2@Wfc)^T bf16, cfc = b2@Wfc ----
    small_prep2<<<24, 256, 0, stream>>>(W2, Wfc, b2, Mt, cfc);

    // ---- V1 = relu(F@W1+b1) @ Mb -> bf16 40-wide (fused MFMA) ----
    gemm1v<<<(NN + 63) / 64, 256, 0, stream>>>(F, W1, b1, Mt, V1);

    // ---- U1 = gather(V1) ----
    gather40<false><<<(NN + 31) / 32, 512, 0, stream>>>(offs, sdst, V1, U1, nullptr,
                                                        nullptr, nullptr, nullptr);

    // ---- out = gather(U1) + deg*cfc + bfc ----
    gather40<true><<<(NN + 31) / 32, 512, 0, stream>>>(offs, sdst, U1, nullptr, out,
                                                       deg, cfc, bfc);
}

// Round 12
// 140.518 us; speedup vs baseline: 1.5326x; 1.1790x over previous
//
#include <hip/hip_runtime.h>

static constexpr int NN = 50000;    // nodes
static constexpr int NE = 1600000;  // edges
static constexpr int CH = 128;
static constexpr int NCLS = 40;

static constexpr int NPB  = 256;                       // nodes per bucket
static constexpr int NBUK = (NN + NPB - 1) / NPB;      // 196
static constexpr int EPB  = 8192;                      // edges per hist block
static constexpr int NHB  = (NE + EPB - 1) / EPB;      // 196
static constexpr int NS   = NBUK * NHB;                // 38416 hist entries
static constexpr int SCAN_B = 256;
static constexpr int NSB  = (NS + SCAN_B - 1) / SCAN_B; // 151 (<=256)
static constexpr int NROWP = ((NN + 63) / 64) * 64;    // 50048 padded V1 rows
static constexpr int PAD = 136;                        // W1^T padded row (bank spread)

typedef __attribute__((ext_vector_type(8))) short bf16x8;
typedef __attribute__((ext_vector_type(4))) float f32x4;

// ---- bf16 helpers (bit-level, RNE) ----
__device__ __forceinline__ float bflo(unsigned v) {
    return __uint_as_float((v & 0xFFFFu) << 16);
}
__device__ __forceinline__ float bfhi(unsigned v) {
    return __uint_as_float(v & 0xFFFF0000u);
}
__device__ __forceinline__ unsigned short f2bf(float f) {
    unsigned u = __float_as_uint(f);
    u += 0x7FFFu + ((u >> 16) & 1u);   // round to nearest even
    return (unsigned short)(u >> 16);
}

// ---------------------------------------------------------------------------
// prep_w1t: Wt_g[c][k] (padded PAD=136) = bf16(W1[k][c]). One-time transpose
// so gemm1v blocks don't each redo a 16K-element convert+transpose.
// ---------------------------------------------------------------------------
__global__ __launch_bounds__(256)
void prep_w1t(const float* __restrict__ W1, unsigned short* __restrict__ Wt_g)
{
    const int idx = blockIdx.x * 256 + threadIdx.x;   // 0..16383
    const int c = idx >> 7;
    const int k = idx & 127;
    Wt_g[c * PAD + k] = f2bf(W1[k * 128 + c]);
}

// ---------------------------------------------------------------------------
// small_prep2: Mt[c][k] = (W2@Wfc)^T bf16, 48x128 (c>=40 zero); cfc = b2@Wfc.
// ---------------------------------------------------------------------------
__global__ __launch_bounds__(256)
void small_prep2(const float* __restrict__ W2, const float* __restrict__ Wfc,
                 const float* __restrict__ b2, unsigned short* __restrict__ Mt,
                 float* __restrict__ cfc)
{
    const int idx = blockIdx.x * 256 + threadIdx.x;   // 0..6143
    if (idx < 48 * 128) {
        const int c = idx >> 7;
        const int k = idx & 127;
        float a = 0.f;
        if (c < NCLS) {
            #pragma unroll 16
            for (int j = 0; j < 128; ++j) a += W2[k * 128 + j] * Wfc[j * NCLS + c];
        }
        Mt[c * 128 + k] = f2bf(a);
    }
    if (blockIdx.x == 0 && threadIdx.x < NCLS) {
        const int c = threadIdx.x;
        float a = 0.f;
        #pragma unroll 16
        for (int j = 0; j < 128; ++j) a += b2[j] * Wfc[j * NCLS + c];
        cfc[c] = a;
    }
}

// ---------------------------------------------------------------------------
// gemm1v: V1 = relu(F @ W1 + b1) @ Mb  (fused two-stage MFMA, V1 bf16 40-wide)
// Block: 256 thr (4 waves), 64 rows. W1^T copied pre-converted from global.
// ---------------------------------------------------------------------------
__global__ __launch_bounds__(256)
void gemm1v(const float* __restrict__ X, const unsigned short* __restrict__ Wt_g,
            const float* __restrict__ b, const unsigned short* __restrict__ Mt,
            unsigned short* __restrict__ V1)
{
    __shared__ __align__(16) unsigned short Wt[128 * PAD];   // W1^T bf16 [c][k]
    __shared__ __align__(16) unsigned short Fa[64 * PAD];    // F tile, then H1 tile
    __shared__ __align__(16) unsigned short Va[64 * NCLS];   // V1 staging (5 KB)
    __shared__ float bl[128];

    const int t = threadIdx.x;
    const int lane = t & 63;
    const int w = t >> 6;

    // ---- copy pre-transposed W1^T into LDS (34.8 KB, uint4) ----
    for (int i = t; i < (128 * PAD) / 8; i += 256)
        reinterpret_cast<uint4*>(Wt)[i] = reinterpret_cast<const uint4*>(Wt_g)[i];
    if (t < 128) bl[t] = b[t];

    // ---- stage Fa (f32 -> bf16) ----
    const int base = blockIdx.x * 64;
    const int nRows = min(64, NN - base);
    {
        const int r = t >> 2;
        const int c0 = (t & 3) * 32;
        if (r < nRows) {
            #pragma unroll
            for (int j = 0; j < 32; j += 4) {
                const float4 v = *reinterpret_cast<const float4*>(&X[(size_t)(base + r) * CH + c0 + j]);
                ushort4 o; o.x = f2bf(v.x); o.y = f2bf(v.y); o.z = f2bf(v.z); o.w = f2bf(v.w);
                *reinterpret_cast<ushort4*>(&Fa[r * PAD + c0 + j]) = o;
            }
        } else {
            #pragma unroll
            for (int j = 0; j < 32; j += 4) {
                ushort4 z; z.x = z.y = z.z = z.w = 0;
                *reinterpret_cast<ushort4*>(&Fa[r * PAD + c0 + j]) = z;
            }
        }
    }
    __syncthreads();

    // ---- stage 1 MFMA: H1 = relu(F@W1+b1) ----
    f32x4 acc[8];
    #pragma unroll
    for (int i = 0; i < 8; ++i) acc[i] = (f32x4){0.f, 0.f, 0.f, 0.f};

    const int arow = w * 16 + (lane & 15);
    const int kgrp = (lane >> 4) * 4;

    #pragma unroll
    for (int ks = 0; ks < 4; ++ks) {
        const int k0 = ks * 32 + kgrp;
        bf16x8 af;
        {
            const short4 lo = *reinterpret_cast<const short4*>(&Fa[arow * PAD + k0]);
            const short4 hi = *reinterpret_cast<const short4*>(&Fa[arow * PAD + k0 + 16]);
            af[0] = lo.x; af[1] = lo.y; af[2] = lo.z; af[3] = lo.w;
            af[4] = hi.x; af[5] = hi.y; af[6] = hi.z; af[7] = hi.w;
        }
        #pragma unroll
        for (int ct = 0; ct < 8; ++ct) {
            const int c = ct * 16 + (lane & 15);
            bf16x8 bf;
            const short4 lo = *reinterpret_cast<const short4*>(&Wt[c * PAD + k0]);
            const short4 hi = *reinterpret_cast<const short4*>(&Wt[c * PAD + k0 + 16]);
            bf[0] = lo.x; bf[1] = lo.y; bf[2] = lo.z; bf[3] = lo.w;
            bf[4] = hi.x; bf[5] = hi.y; bf[6] = hi.z; bf[7] = hi.w;
            acc[ct] = __builtin_amdgcn_mfma_f32_16x16x32_bf16(af, bf, acc[ct], 0, 0, 0);
        }
    }
    __syncthreads();   // Fa (F tile) consumed

    // ---- bias + relu -> H1 tile (bf16) into Fa ----
    #pragma unroll
    for (int ct = 0; ct < 8; ++ct) {
        const int c = ct * 16 + (lane & 15);
        const float bias = bl[c];
        #pragma unroll
        for (int r = 0; r < 4; ++r) {
            const int row = w * 16 + (lane >> 4) * 4 + r;
            Fa[row * PAD + c] = f2bf(fmaxf(acc[ct][r] + bias, 0.f));
        }
    }
    __syncthreads();

    // ---- stage 2 MFMA: V1 = H1 @ Mb (3 col-tiles, cols 0..47) ----
    f32x4 acc2[3];
    #pragma unroll
    for (int i = 0; i < 3; ++i) acc2[i] = (f32x4){0.f, 0.f, 0.f, 0.f};

    #pragma unroll
    for (int ks = 0; ks < 4; ++ks) {
        const int k0 = ks * 32 + kgrp;
        bf16x8 af;
        {
            const short4 lo = *reinterpret_cast<const short4*>(&Fa[arow * PAD + k0]);
            const short4 hi = *reinterpret_cast<const short4*>(&Fa[arow * PAD + k0 + 16]);
            af[0] = lo.x; af[1] = lo.y; af[2] = lo.z; af[3] = lo.w;
            af[4] = hi.x; af[5] = hi.y; af[6] = hi.z; af[7] = hi.w;
        }
        #pragma unroll
        for (int ct = 0; ct < 3; ++ct) {
            const int c = ct * 16 + (lane & 15);
            bf16x8 bf;
            const short4 lo = *reinterpret_cast<const short4*>(&Mt[c * 128 + k0]);
            const short4 hi = *reinterpret_cast<const short4*>(&Mt[c * 128 + k0 + 16]);
            bf[0] = lo.x; bf[1] = lo.y; bf[2] = lo.z; bf[3] = lo.w;
            bf[4] = hi.x; bf[5] = hi.y; bf[6] = hi.z; bf[7] = hi.w;
            acc2[ct] = __builtin_amdgcn_mfma_f32_16x16x32_bf16(af, bf, acc2[ct], 0, 0, 0);
        }
    }

    // ---- stash V1 tile (cols<40) into Va, then coalesced write ----
    #pragma unroll
    for (int ct = 0; ct < 3; ++ct) {
        const int c = ct * 16 + (lane & 15);
        if (c < NCLS) {
            #pragma unroll
            for (int r = 0; r < 4; ++r) {
                const int row = w * 16 + (lane >> 4) * 4 + r;
                Va[row * NCLS + c] = f2bf(acc2[ct][r]);
            }
        }
    }
    __syncthreads();

    // 64 rows x 80 B = 320 uint4 slots, 256 threads -> loop
    for (int i = t; i < 320; i += 256) {
        const int r = i / 5;
        const int q = i % 5;
        *reinterpret_cast<uint4*>(&V1[(size_t)(base + r) * NCLS + q * 8]) =
            *reinterpret_cast<const uint4*>(&Va[r * NCLS + q * 8]);
    }
}

// ---------------------------------------------------------------------------
// Bucketing: per-block LDS histogram over 196 coarse buckets (src>>8).
// int4-vectorized edge reads (4 edges/thread/iter).
// ---------------------------------------------------------------------------
__global__ __launch_bounds__(256)
void bucket_hist(const int* __restrict__ src, int* __restrict__ H)
{
    __shared__ int h[NBUK];
    const int t = threadIdx.x;
    for (int i = t; i < NBUK; i += 256) h[i] = 0;
    __syncthreads();
    const int base4 = blockIdx.x * (EPB / 4);
    const int4* src4 = reinterpret_cast<const int4*>(src);
    for (int i = t; i < EPB / 4; i += 256) {
        const int idx = base4 + i;
        if (idx < NE / 4) {
            const int4 v = src4[idx];
            atomicAdd(&h[v.x >> 8], 1);
            atomicAdd(&h[v.y >> 8], 1);
            atomicAdd(&h[v.z >> 8], 1);
            atomicAdd(&h[v.w >> 8], 1);
        }
    }
    __syncthreads();
    for (int i = t; i < NBUK; i += 256) H[i * NHB + blockIdx.x] = h[i];
}

__global__ __launch_bounds__(SCAN_B)
void scan_local(int* __restrict__ H, int* __restrict__ bsum)
{
    __shared__ int buf[SCAN_B];
    const int t = threadIdx.x;
    const int g = blockIdx.x * SCAN_B + t;
    const int v = (g < NS) ? H[g] : 0;
    buf[t] = v;
    __syncthreads();
    #pragma unroll
    for (int off = 1; off < SCAN_B; off <<= 1) {
        const int x = (t >= off) ? buf[t - off] : 0;
        __syncthreads();
        buf[t] += x;
        __syncthreads();
    }
    if (g < NS) H[g] = buf[t] - v;
    if (t == SCAN_B - 1) bsum[blockIdx.x] = buf[t];
}

__global__ __launch_bounds__(SCAN_B)
void scan_bsums(int* __restrict__ bsum)
{
    __shared__ int buf[SCAN_B];
    const int t = threadIdx.x;
    const int v = (t < NSB) ? bsum[t] : 0;
    buf[t] = v;
    __syncthreads();
    #pragma unroll
    for (int off = 1; off < SCAN_B; off <<= 1) {
        const int x = (t >= off) ? buf[t - off] : 0;
        __syncthreads();
        buf[t] += x;
        __syncthreads();
    }
    if (t < NSB) bsum[t] = buf[t] - v;
    if (t == SCAN_B - 1) bsum[NSB] = buf[t];
}

__global__ __launch_bounds__(SCAN_B)
void scan_add(int* __restrict__ H, const int* __restrict__ bsum)
{
    const int g = blockIdx.x * SCAN_B + threadIdx.x;
    if (g < NS) H[g] += bsum[blockIdx.x];
}

// scatter packed edges ((src&255)<<16 | dst) into bucket-grouped EP
__global__ __launch_bounds__(256)
void bucket_scatter(const int* __restrict__ src, const int* __restrict__ dst,
                    const int* __restrict__ S, int* __restrict__ EP)
{
    __shared__ int cur[NBUK];
    const int t = threadIdx.x;
    for (int i = t; i < NBUK; i += 256) cur[i] = S[i * NHB + blockIdx.x];
    __syncthreads();
    const int base4 = blockIdx.x * (EPB / 4);
    const int4* src4 = reinterpret_cast<const int4*>(src);
    const int4* dst4 = reinterpret_cast<const int4*>(dst);
    for (int i = t; i < EPB / 4; i += 256) {
        const int idx = base4 + i;
        if (idx < NE / 4) {
            const int4 s4 = src4[idx];
            const int4 d4 = dst4[idx];
            int pos;
            pos = atomicAdd(&cur[s4.x >> 8], 1); EP[pos] = ((s4.x & 255) << 16) | d4.x;
            pos = atomicAdd(&cur[s4.y >> 8], 1); EP[pos] = ((s4.y & 255) << 16) | d4.y;
            pos = atomicAdd(&cur[s4.z >> 8], 1); EP[pos] = ((s4.z & 255) << 16) | d4.z;
            pos = atomicAdd(&cur[s4.w >> 8], 1); EP[pos] = ((s4.w & 255) << 16) | d4.w;
        }
    }
}

// ---------------------------------------------------------------------------
// bucket_sort: one 1024-thr block per bucket (only 196 blocks exist -> max
// waves per block for latency hiding). Counting-sort EP segment by local node
// -> CSR (offs, deg) + sorted ushort dsts.
// ---------------------------------------------------------------------------
__global__ __launch_bounds__(1024)
void bucket_sort(const int* __restrict__ S, const int* __restrict__ EP,
                 unsigned short* __restrict__ sdst, int* __restrict__ offs,
                 int* __restrict__ deg)
{
    __shared__ int hist[NPB], cur[NPB], segBeg[NPB + 1], buf[NPB];
    const int t = threadIdx.x;
    const int b = blockIdx.x;
    const int node0 = b * NPB;
    const int nNodes = min(NPB, NN - node0);
    const int beg = S[b * NHB];
    const int end = (b == NBUK - 1) ? NE : S[(b + 1) * NHB];

    if (t < NPB) hist[t] = 0;
    __syncthreads();
    for (int i = beg + t; i < end; i += 1024) atomicAdd(&hist[EP[i] >> 16], 1);
    __syncthreads();

    if (t < NPB) buf[t] = hist[t];
    __syncthreads();
    #pragma unroll
    for (int off = 1; off < NPB; off <<= 1) {
        int x = 0;
        if (t < NPB && t >= off) x = buf[t - off];
        __syncthreads();
        if (t < NPB) buf[t] += x;
        __syncthreads();
    }
    if (t < NPB) segBeg[t] = buf[t] - hist[t];
    if (t == 0) segBeg[NPB] = end - beg;
    __syncthreads();

    if (t < nNodes) {
        offs[node0 + t] = beg + segBeg[t];
        deg[node0 + t] = hist[t];
    }
    if (b == NBUK - 1 && t == 0) offs[NN] = end;
    if (t < NPB) cur[t] = segBeg[t];
    __syncthreads();
    for (int i = beg + t; i < end; i += 1024) {
        const int p = EP[i];
        const int pos = atomicAdd(&cur[p >> 16], 1);
        sdst[beg + pos] = (unsigned short)(p & 0xFFFF);
    }
}

// ---------------------------------------------------------------------------
// gather40: Y[n] = sum over seg of X[dst] (40-ch bf16 rows, 80 B).
// Block 512 thr (8 waves), 4 nodes per wave. 16-lane subgroup per edge slot
// (g = lane>>4), lane L<10 loads uint2 (4 channels). 4-deep unroll -> 16
// edges / 4 independent loads per lane in flight (latency hiding).
// ---------------------------------------------------------------------------
template<bool FINAL>
__global__ __launch_bounds__(512)
void gather40(const int* __restrict__ offs, const unsigned short* __restrict__ sdst,
              const unsigned short* __restrict__ X,
              unsigned short* __restrict__ Yb, float* __restrict__ Yf,
              const int* __restrict__ deg,
              const float* __restrict__ cfc, const float* __restrict__ bfc)
{
    const int t = threadIdx.x;
    const int w = t >> 6;
    const int lane = t & 63;
    const int g = lane >> 4;            // 0..3: edge slot
    const int L = lane & 15;            // channel-group lane
    const int node0 = blockIdx.x * 32 + w * 4;

    float4 cf = make_float4(0.f, 0.f, 0.f, 0.f);
    float4 bfv = make_float4(0.f, 0.f, 0.f, 0.f);
    if (FINAL && L < 10) {
        cf  = *reinterpret_cast<const float4*>(&cfc[L * 4]);
        bfv = *reinterpret_cast<const float4*>(&bfc[L * 4]);
    }

    #pragma unroll
    for (int ni = 0; ni < 4; ++ni) {
        const int n = node0 + ni;
        if (n >= NN) break;
        const int sb = offs[n];
        const int se = offs[n + 1];
        float a0 = 0.f, a1 = 0.f, a2 = 0.f, a3 = 0.f;

        int i = sb;
        for (; i + 16 <= se; i += 16) {
            const int d0 = sdst[i + g];
            const int d1 = sdst[i + 4 + g];
            const int d2 = sdst[i + 8 + g];
            const int d3 = sdst[i + 12 + g];
            if (L < 10) {
                const uint2 v0 = *reinterpret_cast<const uint2*>(&X[(size_t)d0 * NCLS + L * 4]);
                const uint2 v1 = *reinterpret_cast<const uint2*>(&X[(size_t)d1 * NCLS + L * 4]);
                const uint2 v2 = *reinterpret_cast<const uint2*>(&X[(size_t)d2 * NCLS + L * 4]);
                const uint2 v3 = *reinterpret_cast<const uint2*>(&X[(size_t)d3 * NCLS + L * 4]);
                a0 += bflo(v0.x) + bflo(v1.x) + bflo(v2.x) + bflo(v3.x);
                a1 += bfhi(v0.x) + bfhi(v1.x) + bfhi(v2.x) + bfhi(v3.x);
                a2 += bflo(v0.y) + bflo(v1.y) + bflo(v2.y) + bflo(v3.y);
                a3 += bfhi(v0.y) + bfhi(v1.y) + bfhi(v2.y) + bfhi(v3.y);
            }
        }
        for (; i + 4 <= se; i += 4) {
            const int d = sdst[i + g];
            if (L < 10) {
                const uint2 v = *reinterpret_cast<const uint2*>(&X[(size_t)d * NCLS + L * 4]);
                a0 += bflo(v.x); a1 += bfhi(v.x);
                a2 += bflo(v.y); a3 += bfhi(v.y);
            }
        }
        const int rem = se - i;          // 0..3
        if (g < rem) {
            const int d = sdst[i + g];
            if (L < 10) {
                const uint2 v = *reinterpret_cast<const uint2*>(&X[(size_t)d * NCLS + L * 4]);
                a0 += bflo(v.x); a1 += bfhi(v.x);
                a2 += bflo(v.y); a3 += bfhi(v.y);
            }
        }

        a0 += __shfl_xor(a0, 16); a0 += __shfl_xor(a0, 32);
        a1 += __shfl_xor(a1, 16); a1 += __shfl_xor(a1, 32);
        a2 += __shfl_xor(a2, 16); a2 += __shfl_xor(a2, 32);
        a3 += __shfl_xor(a3, 16); a3 += __shfl_xor(a3, 32);

        if (lane < 16 && L < 10) {
            if (FINAL) {
                const float dgn = (float)deg[n];
                float4 o;
                o.x = a0 + dgn * cf.x + bfv.x;
                o.y = a1 + dgn * cf.y + bfv.y;
                o.z = a2 + dgn * cf.z + bfv.z;
                o.w = a3 + dgn * cf.w + bfv.w;
                *reinterpret_cast<float4*>(&Yf[(size_t)n * NCLS + L * 4]) = o;
            } else {
                uint2 o;
                o.x = ((unsigned)f2bf(a1) << 16) | f2bf(a0);
                o.y = ((unsigned)f2bf(a3) << 16) | f2bf(a2);
                *reinterpret_cast<uint2*>(&Yb[(size_t)n * NCLS + L * 4]) = o;
            }
        }
    }
}

extern "C" void kernel_launch(void* const* d_in, const int* in_sizes, int n_in,
                              void* d_out, int out_size, void* d_ws, size_t ws_size,
                              hipStream_t stream) {
    const float* F   = (const float*)d_in[0];  // (1,N,128)
    const int*   EI  = (const int*)  d_in[1];  // (1,2,E) int32
    const float* W1  = (const float*)d_in[3];
    const float* b1  = (const float*)d_in[4];
    const float* W2  = (const float*)d_in[5];
    const float* b2  = (const float*)d_in[6];
    const float* Wfc = (const float*)d_in[7];
    const float* bfc = (const float*)d_in[8];
    float* out = (float*)d_out;

    char* ws = (char*)d_ws;
    size_t off = 0;
    auto take = [&](size_t bytes) { char* p = ws + off; off += (bytes + 15) & ~(size_t)15; return p; };

    unsigned short* V1   = (unsigned short*)take((size_t)NROWP * NCLS * 2); // 4.0 MB
    unsigned short* U1   = (unsigned short*)take((size_t)NN * NCLS * 2);    // 4.0 MB
    unsigned short* sdst = (unsigned short*)take((size_t)NE * 2);           // 3.2 MB
    int*   EP   = (int*)take((size_t)NE * 4);                               // 6.4 MB
    int*   H    = (int*)take((size_t)NS * 4);
    int*   bsum = (int*)take((size_t)(NSB + 1) * 4);
    int*   deg  = (int*)take((size_t)NN * 4);
    int*   offs = (int*)take((size_t)(NN + 1) * 4);
    unsigned short* Mt   = (unsigned short*)take((size_t)48 * 128 * 2);     // 12 KB
    unsigned short* Wt_g = (unsigned short*)take((size_t)128 * PAD * 2);    // 34.8 KB
    float* cfc  = (float*)take((size_t)NCLS * 4);

    const int* src = EI;          // edge_index[0,:]
    const int* dst = EI + NE;     // edge_index[1,:]

    // ---- bucket edges by src>>8, then per-bucket counting sort -> CSR ----
    bucket_hist<<<NHB, 256, 0, stream>>>(src, H);
    scan_local<<<NSB, SCAN_B, 0, stream>>>(H, bsum);
    scan_bsums<<<1, SCAN_B, 0, stream>>>(bsum);
    scan_add<<<NSB, SCAN_B, 0, stream>>>(H, bsum);
    bucket_scatter<<<NHB, 256, 0, stream>>>(src, dst, H, EP);
    bucket_sort<<<NBUK, 1024, 0, stream>>>(H, EP, sdst, offs, deg);

    // ---- weight precompute: W1^T, Mt = (W2@Wfc)^T bf16, cfc = b2@Wfc ----
    prep_w1t<<<64, 256, 0, stream>>>(W1, Wt_g);
    small_prep2<<<24, 256, 0, stream>>>(W2, Wfc, b2, Mt, cfc);

    // ---- V1 = relu(F@W1+b1) @ Mb -> bf16 40-wide (fused MFMA) ----
    gemm1v<<<(NN + 63) / 64, 256, 0, stream>>>(F, Wt_g, b1, Mt, V1);

    // ---- U1 = gather(V1) ----
    gather40<false><<<(NN + 31) / 32, 512, 0, stream>>>(offs, sdst, V1, U1, nullptr,
                                                        nullptr, nullptr, nullptr);

    // ---- out = gather(U1) + deg*cfc + bfc ----
    gather40<true><<<(NN + 31) / 32, 512, 0, stream>>>(offs, sdst, U1, nullptr, out,
                                                       deg, cfc, bfc);
}

// Round 13
// 121.725 us; speedup vs baseline: 1.7693x; 1.1544x over previous
//
#include <hip/hip_runtime.h>

static constexpr int NN = 50000;    // nodes
static constexpr int NE = 1600000;  // edges
static constexpr int CH = 128;
static constexpr int NCLS = 40;

static constexpr int NPB  = 256;                       // nodes per bucket
static constexpr int NBUK = (NN + NPB - 1) / NPB;      // 196
static constexpr int EPB  = 8192;                      // edges per hist block
static constexpr int NHB  = (NE + EPB - 1) / EPB;      // 196
static constexpr int NS   = NBUK * NHB;                // 38416 hist entries
static constexpr int SCAN_B = 256;
static constexpr int NSB  = (NS + SCAN_B - 1) / SCAN_B; // 151 (<=256)
static constexpr int NROWP = ((NN + 63) / 64) * 64;    // 50048 padded V1 rows
static constexpr int PAD = 136;                        // W1^T padded row (bank spread)
static constexpr int GEMM_BLKS = (NN + 63) / 64;       // 782

typedef __attribute__((ext_vector_type(8))) short bf16x8;
typedef __attribute__((ext_vector_type(4))) float f32x4;

// ---- bf16 helpers (bit-level, RNE) ----
__device__ __forceinline__ float bflo(unsigned v) {
    return __uint_as_float((v & 0xFFFFu) << 16);
}
__device__ __forceinline__ float bfhi(unsigned v) {
    return __uint_as_float(v & 0xFFFF0000u);
}
__device__ __forceinline__ unsigned short f2bf(float f) {
    unsigned u = __float_as_uint(f);
    u += 0x7FFFu + ((u >> 16) & 1u);   // round to nearest even
    return (unsigned short)(u >> 16);
}

// ---------------------------------------------------------------------------
// fused_pre: blocks [0,NHB): edge histogram (src>>8) -> H
//            blocks [NHB,NHB+64): W1^T bf16 padded transpose -> Wt_g
//            blocks [NHB+64,NHB+88): Mt=(W2@Wfc)^T bf16 + cfc=b2@Wfc
// ---------------------------------------------------------------------------
__global__ __launch_bounds__(256)
void fused_pre(const int* __restrict__ src, int* __restrict__ H,
               const float* __restrict__ W1, unsigned short* __restrict__ Wt_g,
               const float* __restrict__ W2, const float* __restrict__ Wfc,
               const float* __restrict__ b2, unsigned short* __restrict__ Mt,
               float* __restrict__ cfc)
{
    __shared__ int h[NBUK];
    const int t = threadIdx.x;
    const int b = blockIdx.x;

    if (b < NHB) {
        for (int i = t; i < NBUK; i += 256) h[i] = 0;
        __syncthreads();
        const int base4 = b * (EPB / 4);
        const int4* src4 = reinterpret_cast<const int4*>(src);
        for (int i = t; i < EPB / 4; i += 256) {
            const int idx = base4 + i;
            if (idx < NE / 4) {
                const int4 v = src4[idx];
                atomicAdd(&h[v.x >> 8], 1);
                atomicAdd(&h[v.y >> 8], 1);
                atomicAdd(&h[v.z >> 8], 1);
                atomicAdd(&h[v.w >> 8], 1);
            }
        }
        __syncthreads();
        for (int i = t; i < NBUK; i += 256) H[i * NHB + b] = h[i];
    } else if (b < NHB + 64) {
        const int idx = (b - NHB) * 256 + t;   // 0..16383
        const int c = idx >> 7;
        const int k = idx & 127;
        Wt_g[c * PAD + k] = f2bf(W1[k * 128 + c]);
    } else {
        const int idx = (b - NHB - 64) * 256 + t;   // 0..6143
        if (idx < 48 * 128) {
            const int c = idx >> 7;
            const int k = idx & 127;
            float a = 0.f;
            if (c < NCLS) {
                #pragma unroll 16
                for (int j = 0; j < 128; ++j) a += W2[k * 128 + j] * Wfc[j * NCLS + c];
            }
            Mt[c * 128 + k] = f2bf(a);
        }
        if (b == NHB + 64 && t < NCLS) {
            float a = 0.f;
            #pragma unroll 16
            for (int j = 0; j < 128; ++j) a += b2[j] * Wfc[j * NCLS + t];
            cfc[t] = a;
        }
    }
}

__global__ __launch_bounds__(SCAN_B)
void scan_local(int* __restrict__ H, int* __restrict__ bsum)
{
    __shared__ int buf[SCAN_B];
    const int t = threadIdx.x;
    const int g = blockIdx.x * SCAN_B + t;
    const int v = (g < NS) ? H[g] : 0;
    buf[t] = v;
    __syncthreads();
    #pragma unroll
    for (int off = 1; off < SCAN_B; off <<= 1) {
        const int x = (t >= off) ? buf[t - off] : 0;
        __syncthreads();
        buf[t] += x;
        __syncthreads();
    }
    if (g < NS) H[g] = buf[t] - v;     // exclusive within scan-block
    if (t == SCAN_B - 1) bsum[blockIdx.x] = buf[t];
}

__global__ __launch_bounds__(SCAN_B)
void scan_bsums(int* __restrict__ bsum)
{
    __shared__ int buf[SCAN_B];
    const int t = threadIdx.x;
    const int v = (t < NSB) ? bsum[t] : 0;
    buf[t] = v;
    __syncthreads();
    #pragma unroll
    for (int off = 1; off < SCAN_B; off <<= 1) {
        const int x = (t >= off) ? buf[t - off] : 0;
        __syncthreads();
        buf[t] += x;
        __syncthreads();
    }
    if (t < NSB) bsum[t] = buf[t] - v;  // exclusive base per scan-block
    if (t == SCAN_B - 1) bsum[NSB] = buf[t];
}

// ---------------------------------------------------------------------------
// fused_mid: blocks [0,NHB): bucket_scatter (latency-bound, 196 blocks)
//            blocks [NHB,NHB+782): gemm1v (MFMA-bound) -- independent work
//            overlapped in one launch. S(x) = H[x] + bsum[x>>8] (scan_add
//            folded away).
// ---------------------------------------------------------------------------
__global__ __launch_bounds__(256)
void fused_mid(const int* __restrict__ src, const int* __restrict__ dst,
               const int* __restrict__ H, const int* __restrict__ bsum,
               int* __restrict__ EP,
               const float* __restrict__ X, const unsigned short* __restrict__ Wt_g,
               const float* __restrict__ b, const unsigned short* __restrict__ Mt,
               unsigned short* __restrict__ V1)
{
    __shared__ __align__(16) unsigned short Wt[128 * PAD];   // 34.8 KB
    __shared__ __align__(16) unsigned short Fa[64 * PAD];    // 17.4 KB
    __shared__ __align__(16) unsigned short Va[64 * NCLS];   // 5 KB
    __shared__ float bl[128];
    __shared__ int cur[NBUK];

    const int t = threadIdx.x;

    if (blockIdx.x < NHB) {
        // ---------------- bucket_scatter ----------------
        const int bb = blockIdx.x;
        for (int i = t; i < NBUK; i += 256) {
            const int x = i * NHB + bb;
            cur[i] = H[x] + bsum[x >> 8];
        }
        __syncthreads();
        const int base4 = bb * (EPB / 4);
        const int4* src4 = reinterpret_cast<const int4*>(src);
        const int4* dst4 = reinterpret_cast<const int4*>(dst);
        for (int i = t; i < EPB / 4; i += 256) {
            const int idx = base4 + i;
            if (idx < NE / 4) {
                const int4 s4 = src4[idx];
                const int4 d4 = dst4[idx];
                int pos;
                pos = atomicAdd(&cur[s4.x >> 8], 1); EP[pos] = ((s4.x & 255) << 16) | d4.x;
                pos = atomicAdd(&cur[s4.y >> 8], 1); EP[pos] = ((s4.y & 255) << 16) | d4.y;
                pos = atomicAdd(&cur[s4.z >> 8], 1); EP[pos] = ((s4.z & 255) << 16) | d4.z;
                pos = atomicAdd(&cur[s4.w >> 8], 1); EP[pos] = ((s4.w & 255) << 16) | d4.w;
            }
        }
        return;
    }

    // ---------------- gemm1v: V1 = relu(F@W1+b1) @ Mb ----------------
    const int gb = blockIdx.x - NHB;
    const int lane = t & 63;
    const int w = t >> 6;

    for (int i = t; i < (128 * PAD) / 8; i += 256)
        reinterpret_cast<uint4*>(Wt)[i] = reinterpret_cast<const uint4*>(Wt_g)[i];
    if (t < 128) bl[t] = b[t];

    const int base = gb * 64;
    const int nRows = min(64, NN - base);
    {
        const int r = t >> 2;
        const int c0 = (t & 3) * 32;
        if (r < nRows) {
            #pragma unroll
            for (int j = 0; j < 32; j += 4) {
                const float4 v = *reinterpret_cast<const float4*>(&X[(size_t)(base + r) * CH + c0 + j]);
                ushort4 o; o.x = f2bf(v.x); o.y = f2bf(v.y); o.z = f2bf(v.z); o.w = f2bf(v.w);
                *reinterpret_cast<ushort4*>(&Fa[r * PAD + c0 + j]) = o;
            }
        } else {
            #pragma unroll
            for (int j = 0; j < 32; j += 4) {
                ushort4 z; z.x = z.y = z.z = z.w = 0;
                *reinterpret_cast<ushort4*>(&Fa[r * PAD + c0 + j]) = z;
            }
        }
    }
    __syncthreads();

    f32x4 acc[8];
    #pragma unroll
    for (int i = 0; i < 8; ++i) acc[i] = (f32x4){0.f, 0.f, 0.f, 0.f};

    const int arow = w * 16 + (lane & 15);
    const int kgrp = (lane >> 4) * 4;

    #pragma unroll
    for (int ks = 0; ks < 4; ++ks) {
        const int k0 = ks * 32 + kgrp;
        bf16x8 af;
        {
            const short4 lo = *reinterpret_cast<const short4*>(&Fa[arow * PAD + k0]);
            const short4 hi = *reinterpret_cast<const short4*>(&Fa[arow * PAD + k0 + 16]);
            af[0] = lo.x; af[1] = lo.y; af[2] = lo.z; af[3] = lo.w;
            af[4] = hi.x; af[5] = hi.y; af[6] = hi.z; af[7] = hi.w;
        }
        #pragma unroll
        for (int ct = 0; ct < 8; ++ct) {
            const int c = ct * 16 + (lane & 15);
            bf16x8 bf;
            const short4 lo = *reinterpret_cast<const short4*>(&Wt[c * PAD + k0]);
            const short4 hi = *reinterpret_cast<const short4*>(&Wt[c * PAD + k0 + 16]);
            bf[0] = lo.x; bf[1] = lo.y; bf[2] = lo.z; bf[3] = lo.w;
            bf[4] = hi.x; bf[5] = hi.y; bf[6] = hi.z; bf[7] = hi.w;
            acc[ct] = __builtin_amdgcn_mfma_f32_16x16x32_bf16(af, bf, acc[ct], 0, 0, 0);
        }
    }
    __syncthreads();

    #pragma unroll
    for (int ct = 0; ct < 8; ++ct) {
        const int c = ct * 16 + (lane & 15);
        const float bias = bl[c];
        #pragma unroll
        for (int r = 0; r < 4; ++r) {
            const int row = w * 16 + (lane >> 4) * 4 + r;
            Fa[row * PAD + c] = f2bf(fmaxf(acc[ct][r] + bias, 0.f));
        }
    }
    __syncthreads();

    f32x4 acc2[3];
    #pragma unroll
    for (int i = 0; i < 3; ++i) acc2[i] = (f32x4){0.f, 0.f, 0.f, 0.f};

    #pragma unroll
    for (int ks = 0; ks < 4; ++ks) {
        const int k0 = ks * 32 + kgrp;
        bf16x8 af;
        {
            const short4 lo = *reinterpret_cast<const short4*>(&Fa[arow * PAD + k0]);
            const short4 hi = *reinterpret_cast<const short4*>(&Fa[arow * PAD + k0 + 16]);
            af[0] = lo.x; af[1] = lo.y; af[2] = lo.z; af[3] = lo.w;
            af[4] = hi.x; af[5] = hi.y; af[6] = hi.z; af[7] = hi.w;
        }
        #pragma unroll
        for (int ct = 0; ct < 3; ++ct) {
            const int c = ct * 16 + (lane & 15);
            bf16x8 bf;
            const short4 lo = *reinterpret_cast<const short4*>(&Mt[c * 128 + k0]);
            const short4 hi = *reinterpret_cast<const short4*>(&Mt[c * 128 + k0 + 16]);
            bf[0] = lo.x; bf[1] = lo.y; bf[2] = lo.z; bf[3] = lo.w;
            bf[4] = hi.x; bf[5] = hi.y; bf[6] = hi.z; bf[7] = hi.w;
            acc2[ct] = __builtin_amdgcn_mfma_f32_16x16x32_bf16(af, bf, acc2[ct], 0, 0, 0);
        }
    }

    #pragma unroll
    for (int ct = 0; ct < 3; ++ct) {
        const int c = ct * 16 + (lane & 15);
        if (c < NCLS) {
            #pragma unroll
            for (int r = 0; r < 4; ++r) {
                const int row = w * 16 + (lane >> 4) * 4 + r;
                Va[row * NCLS + c] = f2bf(acc2[ct][r]);
            }
        }
    }
    __syncthreads();

    for (int i = t; i < 320; i += 256) {
        const int r = i / 5;
        const int q = i % 5;
        *reinterpret_cast<uint4*>(&V1[(size_t)(base + r) * NCLS + q * 8]) =
            *reinterpret_cast<const uint4*>(&Va[r * NCLS + q * 8]);
    }
}

// ---------------------------------------------------------------------------
// bucket_sort: one 1024-thr block per bucket. Counting-sort EP segment by
// local node -> CSR (offs, deg) + sorted ushort dsts. S(x)=H[x]+bsum[x>>8].
// ---------------------------------------------------------------------------
__global__ __launch_bounds__(1024)
void bucket_sort(const int* __restrict__ H, const int* __restrict__ bsum,
                 const int* __restrict__ EP,
                 unsigned short* __restrict__ sdst, int* __restrict__ offs,
                 int* __restrict__ deg)
{
    __shared__ int hist[NPB], cur[NPB], segBeg[NPB + 1], buf[NPB];
    const int t = threadIdx.x;
    const int b = blockIdx.x;
    const int node0 = b * NPB;
    const int nNodes = min(NPB, NN - node0);
    const int xb = b * NHB;
    const int beg = H[xb] + bsum[xb >> 8];
    int end;
    if (b == NBUK - 1) end = NE;
    else { const int xe = (b + 1) * NHB; end = H[xe] + bsum[xe >> 8]; }

    if (t < NPB) hist[t] = 0;
    __syncthreads();
    for (int i = beg + t; i < end; i += 1024) atomicAdd(&hist[EP[i] >> 16], 1);
    __syncthreads();

    if (t < NPB) buf[t] = hist[t];
    __syncthreads();
    #pragma unroll
    for (int off = 1; off < NPB; off <<= 1) {
        int x = 0;
        if (t < NPB && t >= off) x = buf[t - off];
        __syncthreads();
        if (t < NPB) buf[t] += x;
        __syncthreads();
    }
    if (t < NPB) segBeg[t] = buf[t] - hist[t];
    if (t == 0) segBeg[NPB] = end - beg;
    __syncthreads();

    if (t < nNodes) {
        offs[node0 + t] = beg + segBeg[t];
        deg[node0 + t] = hist[t];
    }
    if (b == NBUK - 1 && t == 0) offs[NN] = end;
    if (t < NPB) cur[t] = segBeg[t];
    __syncthreads();
    for (int i = beg + t; i < end; i += 1024) {
        const int p = EP[i];
        const int pos = atomicAdd(&cur[p >> 16], 1);
        sdst[beg + pos] = (unsigned short)(p & 0xFFFF);
    }
}

// ---------------------------------------------------------------------------
// gather40: Y[n] = sum over seg of X[dst] (40-ch bf16 rows, 80 B).
// Block 512 thr (8 waves), 4 nodes per wave. 16-lane subgroup per edge slot,
// lane L<10 loads uint2. 4-deep unroll for latency hiding.
// ---------------------------------------------------------------------------
template<bool FINAL>
__global__ __launch_bounds__(512)
void gather40(const int* __restrict__ offs, const unsigned short* __restrict__ sdst,
              const unsigned short* __restrict__ X,
              unsigned short* __restrict__ Yb, float* __restrict__ Yf,
              const int* __restrict__ deg,
              const float* __restrict__ cfc, const float* __restrict__ bfc)
{
    const int t = threadIdx.x;
    const int w = t >> 6;
    const int lane = t & 63;
    const int g = lane >> 4;            // 0..3: edge slot
    const int L = lane & 15;            // channel-group lane
    const int node0 = blockIdx.x * 32 + w * 4;

    float4 cf = make_float4(0.f, 0.f, 0.f, 0.f);
    float4 bfv = make_float4(0.f, 0.f, 0.f, 0.f);
    if (FINAL && L < 10) {
        cf  = *reinterpret_cast<const float4*>(&cfc[L * 4]);
        bfv = *reinterpret_cast<const float4*>(&bfc[L * 4]);
    }

    #pragma unroll
    for (int ni = 0; ni < 4; ++ni) {
        const int n = node0 + ni;
        if (n >= NN) break;
        const int sb = offs[n];
        const int se = offs[n + 1];
        float a0 = 0.f, a1 = 0.f, a2 = 0.f, a3 = 0.f;

        int i = sb;
        for (; i + 16 <= se; i += 16) {
            const int d0 = sdst[i + g];
            const int d1 = sdst[i + 4 + g];
            const int d2 = sdst[i + 8 + g];
            const int d3 = sdst[i + 12 + g];
            if (L < 10) {
                const uint2 v0 = *reinterpret_cast<const uint2*>(&X[(size_t)d0 * NCLS + L * 4]);
                const uint2 v1 = *reinterpret_cast<const uint2*>(&X[(size_t)d1 * NCLS + L * 4]);
                const uint2 v2 = *reinterpret_cast<const uint2*>(&X[(size_t)d2 * NCLS + L * 4]);
                const uint2 v3 = *reinterpret_cast<const uint2*>(&X[(size_t)d3 * NCLS + L * 4]);
                a0 += bflo(v0.x) + bflo(v1.x) + bflo(v2.x) + bflo(v3.x);
                a1 += bfhi(v0.x) + bfhi(v1.x) + bfhi(v2.x) + bfhi(v3.x);
                a2 += bflo(v0.y) + bflo(v1.y) + bflo(v2.y) + bflo(v3.y);
                a3 += bfhi(v0.y) + bfhi(v1.y) + bfhi(v2.y) + bfhi(v3.y);
            }
        }
        for (; i + 4 <= se; i += 4) {
            const int d = sdst[i + g];
            if (L < 10) {
                const uint2 v = *reinterpret_cast<const uint2*>(&X[(size_t)d * NCLS + L * 4]);
                a0 += bflo(v.x); a1 += bfhi(v.x);
                a2 += bflo(v.y); a3 += bfhi(v.y);
            }
        }
        const int rem = se - i;          // 0..3
        if (g < rem) {
            const int d = sdst[i + g];
            if (L < 10) {
                const uint2 v = *reinterpret_cast<const uint2*>(&X[(size_t)d * NCLS + L * 4]);
                a0 += bflo(v.x); a1 += bfhi(v.x);
                a2 += bflo(v.y); a3 += bfhi(v.y);
            }
        }

        a0 += __shfl_xor(a0, 16); a0 += __shfl_xor(a0, 32);
        a1 += __shfl_xor(a1, 16); a1 += __shfl_xor(a1, 32);
        a2 += __shfl_xor(a2, 16); a2 += __shfl_xor(a2, 32);
        a3 += __shfl_xor(a3, 16); a3 += __shfl_xor(a3, 32);

        if (lane < 16 && L < 10) {
            if (FINAL) {
                const float dgn = (float)deg[n];
                float4 o;
                o.x = a0 + dgn * cf.x + bfv.x;
                o.y = a1 + dgn * cf.y + bfv.y;
                o.z = a2 + dgn * cf.z + bfv.z;
                o.w = a3 + dgn * cf.w + bfv.w;
                *reinterpret_cast<float4*>(&Yf[(size_t)n * NCLS + L * 4]) = o;
            } else {
                uint2 o;
                o.x = ((unsigned)f2bf(a1) << 16) | f2bf(a0);
                o.y = ((unsigned)f2bf(a3) << 16) | f2bf(a2);
                *reinterpret_cast<uint2*>(&Yb[(size_t)n * NCLS + L * 4]) = o;
            }
        }
    }
}

extern "C" void kernel_launch(void* const* d_in, const int* in_sizes, int n_in,
                              void* d_out, int out_size, void* d_ws, size_t ws_size,
                              hipStream_t stream) {
    const float* F   = (const float*)d_in[0];  // (1,N,128)
    const int*   EI  = (const int*)  d_in[1];  // (1,2,E) int32
    const float* W1  = (const float*)d_in[3];
    const float* b1  = (const float*)d_in[4];
    const float* W2  = (const float*)d_in[5];
    const float* b2  = (const float*)d_in[6];
    const float* Wfc = (const float*)d_in[7];
    const float* bfc = (const float*)d_in[8];
    float* out = (float*)d_out;

    char* ws = (char*)d_ws;
    size_t off = 0;
    auto take = [&](size_t bytes) { char* p = ws + off; off += (bytes + 15) & ~(size_t)15; return p; };

    unsigned short* V1   = (unsigned short*)take((size_t)NROWP * NCLS * 2); // 4.0 MB
    unsigned short* U1   = (unsigned short*)take((size_t)NN * NCLS * 2);    // 4.0 MB
    unsigned short* sdst = (unsigned short*)take((size_t)NE * 2);           // 3.2 MB
    int*   EP   = (int*)take((size_t)NE * 4);                               // 6.4 MB
    int*   H    = (int*)take((size_t)NS * 4);
    int*   bsum = (int*)take((size_t)(NSB + 1) * 4);
    int*   deg  = (int*)take((size_t)NN * 4);
    int*   offs = (int*)take((size_t)(NN + 1) * 4);
    unsigned short* Mt   = (unsigned short*)take((size_t)48 * 128 * 2);     // 12 KB
    unsigned short* Wt_g = (unsigned short*)take((size_t)128 * PAD * 2);    // 34.8 KB
    float* cfc  = (float*)take((size_t)NCLS * 4);

    const int* src = EI;          // edge_index[0,:]
    const int* dst = EI + NE;     // edge_index[1,:]

    // K1: histogram + weight preps (independent, one launch)
    fused_pre<<<NHB + 64 + 24, 256, 0, stream>>>(src, H, W1, Wt_g, W2, Wfc, b2, Mt, cfc);

    // K2-K3: two-level exclusive scan (scan_add folded into consumers)
    scan_local<<<NSB, SCAN_B, 0, stream>>>(H, bsum);
    scan_bsums<<<1, SCAN_B, 0, stream>>>(bsum);

    // K4: bucket_scatter (196 blocks) + gemm1v (782 blocks) overlapped
    fused_mid<<<NHB + GEMM_BLKS, 256, 0, stream>>>(src, dst, H, bsum, EP,
                                                   F, Wt_g, b1, Mt, V1);

    // K5: per-bucket counting sort -> CSR + sdst
    bucket_sort<<<NBUK, 1024, 0, stream>>>(H, bsum, EP, sdst, offs, deg);

    // K6: U1 = gather(V1)
    gather40<false><<<(NN + 31) / 32, 512, 0, stream>>>(offs, sdst, V1, U1, nullptr,
                                                        nullptr, nullptr, nullptr);

    // K7: out = gather(U1) + deg*cfc + bfc
    gather40<true><<<(NN + 31) / 32, 512, 0, stream>>>(offs, sdst, U1, nullptr, out,
                                                       deg, cfc, bfc);
}